// Round 6
// baseline (4134.989 us; speedup 1.0000x reference)
//
#include <hip/hip_runtime.h>
#include <hip/hip_bf16.h>
#include <cstdint>
#include <cstddef>

// ---------------------------------------------------------------------------
// AudioEncoder (Whisper-style) forward for MI355X.
// B=8, T=4096, n_mels=128, D=1024, H=8 heads (hd=128), F=4096, L=6, S=1024.
// GEMMs: 256x256 tile, 8 waves, BK=64, 8-phase schedule with counted vmcnt,
// XOR-swizzled LDS (T2), setprio around MFMA clusters (T5).
// Attention: flash kernel with LDS-staged double-buffered K/V (unchanged).
// ---------------------------------------------------------------------------

typedef __bf16 bf16_t;
typedef __bf16 bf16x8 __attribute__((ext_vector_type(8)));
typedef __bf16 bf16x4 __attribute__((ext_vector_type(4)));
typedef float  floatx4 __attribute__((ext_vector_type(4)));

#define NB   8
#define NS   1024
#define ND   1024
#define NT   4096
#define NT1  2048

#define MFMA16(a, b, c) __builtin_amdgcn_mfma_f32_16x16x32_bf16(a, b, c, 0, 0, 0)

#define SBAR() do { __builtin_amdgcn_sched_barrier(0); \
                    __builtin_amdgcn_s_barrier();      \
                    __builtin_amdgcn_sched_barrier(0); } while (0)

__device__ __forceinline__ float gelu_f(float x) {
  return 0.5f * x * (1.0f + erff(x * 0.70710678118654752440f));
}

__device__ __forceinline__ void gload16(const void* g, void* l) {
  __builtin_amdgcn_global_load_lds(
      (__attribute__((address_space(1))) void*)(const_cast<void*>(g)),
      (__attribute__((address_space(3))) void*)l, 16, 0, 0);
}

enum { EPI_BF16 = 0, EPI_GELU_BF16 = 2, EPI_GELU_F3 = 3, EPI_GELU_F32 = 3, EPI_RES_F32 = 4, EPI_QKV = 5 };

// C = A (M,K) @ B^T, B stored (N,K) row-major. 256x256 tile, 8 waves (2Mx4N),
// per-wave 128x64 C. BK=64, double-buffered LDS, 8-phase (4/K-tile) schedule:
// per phase {ds_reads || stage 1 half-tile -> barrier -> setprio+16 MFMA ->
// barrier}; counted s_waitcnt vmcnt(4) once per K-tile. LDS XOR-swizzled
// (linear gload_lds dest + inverse-swizzled global source, same XOR on reads).
template<int EPI>
__global__ __launch_bounds__(512, 2)
void gemm_bt(const bf16_t* __restrict__ A, long lda,
             const bf16_t* __restrict__ Bm, long ldb,
             void* Cv, long ldc,
             const float* __restrict__ bias, const float* res,
             int K, int swz,
             bf16_t* out2, bf16_t* out3, const float* __restrict__ bias2,
             const float2* __restrict__ rtab)
{
  __shared__ bf16_t sA[2][16384];   // [buf][half*8192 + seg*512 + ...]
  __shared__ bf16_t sB[2][16384];
  const int tid  = threadIdx.x;
  const int wid  = tid >> 6;
  const int lane = tid & 63;
  const int lo = lane & 15, g = lane >> 4;
  const int wr = wid >> 2, wc = wid & 3;   // 2M x 4N wave grid

  int bx = blockIdx.x, by = blockIdx.y;
  if (swz) {               // bijective XCD-chunked remap (grid size % 8 == 0)
    const int gx = gridDim.x;
    const int n  = gx * gridDim.y;
    int id = bx + by * gx;
    id = (id & 7) * (n >> 3) + (id >> 3);
    bx = id % gx; by = id / gx;
  }
  const int m0 = bx * 256, n0 = by * 256;
  const int NTK = K >> 6;              // K-tiles of 64

  const int srow = lane >> 3;                       // row within 8-row segment
  const int scol = 8 * ((lane & 7) ^ srow);         // inverse-swizzled src col

  auto stageA = [&](int t, int half) {   // A half-tile: rows [half*128,+128)
    if (t >= NTK) return;
    const int kb = t << 6, buf = t & 1;
#pragma unroll
    for (int j = 0; j < 2; ++j) {
      const int sg = wid * 2 + j;        // 16 segments x 1024B
      gload16(A + (long)(m0 + half * 128 + sg * 8 + srow) * lda + kb + scol,
              &sA[buf][half * 8192 + sg * 512]);
    }
  };
  auto stageB = [&](int t, int half) {
    if (t >= NTK) return;
    const int kb = t << 6, buf = t & 1;
#pragma unroll
    for (int j = 0; j < 2; ++j) {
      const int sg = wid * 2 + j;
      gload16(Bm + (long)(n0 + half * 128 + sg * 8 + srow) * ldb + kb + scol,
              &sB[buf][half * 8192 + sg * 512]);
    }
  };

  const int rsw = (lo & 7) << 4;       // read-side XOR (bytes); row&7 == lo&7
  auto rdA = [&](int buf, int mi, int ks) -> bf16x8 {
    return *(const bf16x8*)((const char*)&sA[buf][wr * 8192]
        + (mi * 16 + lo) * 128 + ((ks * 64 + g * 16) ^ rsw));
  };
  auto rdB = [&](int buf, int ni, int ks) -> bf16x8 {
    return *(const bf16x8*)((const char*)&sB[buf][(wc >> 1) * 8192]
        + ((wc & 1) * 64 + ni * 16 + lo) * 128 + ((ks * 64 + g * 16) ^ rsw));
  };

  floatx4 acc[8][4] = {};

  // prologue: issue order matches steady-state sequence (A0,A1,B0,B1 per tile)
  stageA(0, 0); stageA(0, 1); stageB(0, 0); stageB(0, 1);
  stageA(1, 0); stageA(1, 1);
  asm volatile("s_waitcnt vmcnt(4)" ::: "memory");   // tile0 fully landed
  SBAR();

#pragma unroll 1
  for (int s = 0; s < NTK; ++s) {
    const int buf = s & 1;
    bf16x8 a0[4][2], a1[4][2], b01[2][2], b23[2][2];
    // ---- P1: read a0,b01; stage B(s+1).h0; MFMA acc[0..3][0..1] ----
#pragma unroll
    for (int mi = 0; mi < 4; ++mi)
#pragma unroll
      for (int ks = 0; ks < 2; ++ks) a0[mi][ks] = rdA(buf, mi, ks);
#pragma unroll
    for (int ni = 0; ni < 2; ++ni)
#pragma unroll
      for (int ks = 0; ks < 2; ++ks) b01[ni][ks] = rdB(buf, ni, ks);
    stageB(s + 1, 0);
    SBAR();
    __builtin_amdgcn_s_setprio(1);
#pragma unroll
    for (int mi = 0; mi < 4; ++mi)
#pragma unroll
      for (int ni = 0; ni < 2; ++ni)
#pragma unroll
        for (int ks = 0; ks < 2; ++ks)
          acc[mi][ni] = MFMA16(a0[mi][ks], b01[ni][ks], acc[mi][ni]);
    __builtin_amdgcn_s_setprio(0);
    SBAR();
    // ---- P2: read a1,b23; stage B(s+1).h1; MFMA acc[0..3][2..3] ----
#pragma unroll
    for (int mi = 0; mi < 4; ++mi)
#pragma unroll
      for (int ks = 0; ks < 2; ++ks) a1[mi][ks] = rdA(buf, mi + 4, ks);
#pragma unroll
    for (int ni = 0; ni < 2; ++ni)
#pragma unroll
      for (int ks = 0; ks < 2; ++ks) b23[ni][ks] = rdB(buf, ni + 2, ks);
    stageB(s + 1, 1);
    SBAR();
    __builtin_amdgcn_s_setprio(1);
#pragma unroll
    for (int mi = 0; mi < 4; ++mi)
#pragma unroll
      for (int ni = 0; ni < 2; ++ni)
#pragma unroll
        for (int ks = 0; ks < 2; ++ks)
          acc[mi][ni + 2] = MFMA16(a0[mi][ks], b23[ni][ks], acc[mi][ni + 2]);
    __builtin_amdgcn_s_setprio(0);
    SBAR();
    // ---- P3: stage A(s+2).h0; MFMA acc[4..7][2..3] (regs only) ----
    stageA(s + 2, 0);
    SBAR();
    __builtin_amdgcn_s_setprio(1);
#pragma unroll
    for (int mi = 0; mi < 4; ++mi)
#pragma unroll
      for (int ni = 0; ni < 2; ++ni)
#pragma unroll
        for (int ks = 0; ks < 2; ++ks)
          acc[mi + 4][ni + 2] = MFMA16(a1[mi][ks], b23[ni][ks], acc[mi + 4][ni + 2]);
    __builtin_amdgcn_s_setprio(0);
    SBAR();
    // ---- P4: re-read b01; stage A(s+2).h1; MFMA acc[4..7][0..1]; vmcnt ----
#pragma unroll
    for (int ni = 0; ni < 2; ++ni)
#pragma unroll
      for (int ks = 0; ks < 2; ++ks) b01[ni][ks] = rdB(buf, ni, ks);
    stageA(s + 2, 1);
    SBAR();
    __builtin_amdgcn_s_setprio(1);
#pragma unroll
    for (int mi = 0; mi < 4; ++mi)
#pragma unroll
      for (int ni = 0; ni < 2; ++ni)
#pragma unroll
        for (int ks = 0; ks < 2; ++ks)
          acc[mi + 4][ni] = MFMA16(a1[mi][ks], b01[ni][ks], acc[mi + 4][ni]);
    __builtin_amdgcn_s_setprio(0);
    if (s + 2 < NTK) { asm volatile("s_waitcnt vmcnt(4)" ::: "memory"); }
    else             { asm volatile("s_waitcnt vmcnt(0)" ::: "memory"); }
    SBAR();
  }

  // ---- epilogue ----
  if constexpr (EPI == EPI_QKV) {
    const int sect = n0 >> 10;        // 0=Q 1=K 2=V (256-tiles never straddle)
#pragma unroll
    for (int ni = 0; ni < 4; ++ni) {
      const int col = n0 + wc * 64 + ni * 16 + lo;
      const int c10 = col & 1023;
      float bvs = 0.0f;
      if (sect == 0) bvs = bias[c10];
      else if (sect == 2) bvs = bias2[c10];
#pragma unroll
      for (int mi = 0; mi < 8; ++mi) {
#pragma unroll
        for (int r = 0; r < 4; ++r) {
          const int row = m0 + wr * 128 + mi * 16 + g * 4 + r;
          const int s = row & 1023;
          float val = acc[mi][ni][r] + bvs;
          if (sect < 2) {             // rope + scale (table pre-scaled)
            const float2 t = rtab[(s << 6) + ((col & 127) >> 1)];
            const float p = __shfl_xor(val, 1);
            val = val * t.x + p * ((col & 1) ? t.y : -t.y);
            bf16_t* dst = sect ? out2 : (bf16_t*)Cv;
            dst[(long)row * 1024 + c10] = (bf16_t)val;
          } else {                    // vt[b][h*128+d][s]
            out3[((long)(row >> 10) << 20) + ((long)(col - 2048) << 10) + s] = (bf16_t)val;
          }
        }
      }
    }
    return;
  }

#pragma unroll
  for (int ni = 0; ni < 4; ++ni) {
    const int col = n0 + wc * 64 + ni * 16 + lo;
    const float bvs = bias ? bias[col] : 0.0f;
#pragma unroll
    for (int mi = 0; mi < 8; ++mi) {
#pragma unroll
      for (int r = 0; r < 4; ++r) {
        const int row = m0 + wr * 128 + mi * 16 + g * 4 + r;
        float v = acc[mi][ni][r] + bvs;
        if constexpr (EPI == EPI_BF16) {
          ((bf16_t*)Cv)[(long)row * ldc + col] = (bf16_t)v;
        } else if constexpr (EPI == EPI_GELU_BF16) {
          ((bf16_t*)Cv)[(long)row * ldc + col] = (bf16_t)gelu_f(v);
        } else if constexpr (EPI == EPI_GELU_F32) {
          ((float*)Cv)[(long)row * ldc + col] = gelu_f(v);
        } else {  // EPI_RES_F32
          const long idx = (long)row * ldc + col;
          ((float*)Cv)[idx] = res[idx] + v;
        }
      }
    }
  }
}

// ---------------------------------------------------------------------------
// Flash attention (unchanged from round 5): grid (S/128, B*H), 4 waves/block.
// ---------------------------------------------------------------------------
__global__ __launch_bounds__(256)
void flash_kernel(const bf16_t* __restrict__ q, const bf16_t* __restrict__ k,
                  const bf16_t* __restrict__ vt, bf16_t* __restrict__ o,
                  const int* __restrict__ xlen)
{
  __shared__ bf16_t sK[2][4096];   // [kv=64][d=128], rows swizzled
  __shared__ bf16_t sV[2][4096];   // [d=128][kv=64], rows swizzled
  __shared__ bf16_t sP[4][2048];   // per-wave [q=32][kv=64], swizzled
  const int tid = threadIdx.x, w = tid >> 6, lane = tid & 63;
  const int lo = lane & 15, g = lane >> 4;
  const int bh = blockIdx.y, b = bh >> 3, h = bh & 7;
  const int q0 = blockIdx.x * 128 + w * 32;
  const int nv  = xlen[b] >> 2;
  const int nkt = (nv + 63) >> 6;
  const long base = (long)b * 1048576 + (long)h * 128;
  const bf16_t* Qp = q + base;
  const bf16_t* Kp = k + base;
  const bf16_t* Vp = vt + (long)b * 1048576 + ((long)h << 17);

  auto stageKV = [&](int kt, int buf) {
    const int kv0 = kt << 6;
#pragma unroll
    for (int j = 0; j < 4; ++j) {
      const int seg = (w << 2) + j;
      {
        const int row = (seg << 2) + (lane >> 4);
        const int col = ((lane & 15) << 3) ^ ((row & 7) << 3);
        gload16(Kp + (long)(kv0 + row) * 1024 + col, &sK[buf][seg * 512]);
      }
      {
        const int row = (seg << 3) + (lane >> 3);
        const int col = ((lane & 7) << 3) ^ ((row & 7) << 3);
        gload16(Vp + (long)row * 1024 + kv0 + col, &sV[buf][seg * 512]);
      }
    }
  };

  bf16x8 qf[2][4];
#pragma unroll
  for (int mi = 0; mi < 2; ++mi)
#pragma unroll
    for (int ks = 0; ks < 4; ++ks)
      qf[mi][ks] = *reinterpret_cast<const bf16x8*>(
          Qp + (long)(q0 + mi * 16 + lo) * 1024 + ks * 32 + g * 8);

  floatx4 of[2][8] = {};
  float m[2][4], l[2][4];
#pragma unroll
  for (int mi = 0; mi < 2; ++mi)
#pragma unroll
    for (int r = 0; r < 4; ++r) { m[mi][r] = -1e30f; l[mi][r] = 0.0f; }

  const char* kbase = (const char*)&sK[0][0];
  const char* vbase = (const char*)&sV[0][0];
  char* pbase = (char*)&sP[w][0];
  const int swzL = (lo & 7) << 4;

  stageKV(0, 0);
  __syncthreads();
  int cur = 0;
#pragma unroll 1
  for (int kt = 0; kt < nkt; ++kt) {
    const int kv0 = kt << 6;
    if (kt + 1 < nkt) stageKV(kt + 1, cur ^ 1);

    floatx4 s[2][4] = {};
#pragma unroll
    for (int ni = 0; ni < 4; ++ni) {
#pragma unroll
      for (int ks = 0; ks < 4; ++ks) {
        const bf16x8 bv = *reinterpret_cast<const bf16x8*>(
            kbase + cur * 8192 + (ni * 16 + lo) * 256 + ((ks * 64 + (g << 4)) ^ swzL));
        s[0][ni] = MFMA16(qf[0][ks], bv, s[0][ni]);
        s[1][ni] = MFMA16(qf[1][ks], bv, s[1][ni]);
      }
    }

#pragma unroll
    for (int mi = 0; mi < 2; ++mi) {
#pragma unroll
      for (int r = 0; r < 4; ++r) {
        float vv[4]; float pm = -1e30f;
#pragma unroll
        for (int ni = 0; ni < 4; ++ni) {
          float val = s[mi][ni][r];
          if (kv0 + ni * 16 + lo >= nv) val = -1e30f;
          vv[ni] = val; pm = fmaxf(pm, val);
        }
        pm = fmaxf(pm, __shfl_xor(pm, 1)); pm = fmaxf(pm, __shfl_xor(pm, 2));
        pm = fmaxf(pm, __shfl_xor(pm, 4)); pm = fmaxf(pm, __shfl_xor(pm, 8));
        const float mo = m[mi][r];
        const float mn = fmaxf(mo, pm);
        const float sc = __expf(mo - mn);
        const int qrow = mi * 16 + g * 4 + r;
        const int sw = (qrow & 7) << 4;
        float ss = 0.0f;
#pragma unroll
        for (int ni = 0; ni < 4; ++ni) {
          const float p = __expf(vv[ni] - mn);
          ss += p;
          *(bf16_t*)(pbase + qrow * 128 + (((ni << 5) + (lo << 1)) ^ sw)) = (bf16_t)p;
        }
        ss += __shfl_xor(ss, 1); ss += __shfl_xor(ss, 2);
        ss += __shfl_xor(ss, 4); ss += __shfl_xor(ss, 8);
        l[mi][r] = l[mi][r] * sc + ss;
        m[mi][r] = mn;
#pragma unroll
        for (int nd = 0; nd < 8; ++nd) of[mi][nd][r] *= sc;
      }
    }

    asm volatile("s_waitcnt lgkmcnt(0)" ::: "memory");
    __builtin_amdgcn_sched_barrier(0);

#pragma unroll
    for (int ks = 0; ks < 2; ++ks) {
      bf16x8 av0 = *reinterpret_cast<const bf16x8*>(
          pbase + (0 * 16 + lo) * 128 + (((ks << 6) + (g << 4)) ^ swzL));
      bf16x8 av1 = *reinterpret_cast<const bf16x8*>(
          pbase + (1 * 16 + lo) * 128 + (((ks << 6) + (g << 4)) ^ swzL));
#pragma unroll
      for (int nd = 0; nd < 8; ++nd) {
        const bf16x8 bv = *reinterpret_cast<const bf16x8*>(
            vbase + cur * 8192 + (nd * 16 + lo) * 128 + (((ks << 6) + (g << 4)) ^ swzL));
        of[0][nd] = MFMA16(av0, bv, of[0][nd]);
        of[1][nd] = MFMA16(av1, bv, of[1][nd]);
      }
    }
    __syncthreads();
    cur ^= 1;
  }

#pragma unroll
  for (int mi = 0; mi < 2; ++mi)
#pragma unroll
    for (int r = 0; r < 4; ++r) {
      const float inv = 1.0f / l[mi][r];
      const long rb = base + (long)(q0 + mi * 16 + g * 4 + r) * 1024;
#pragma unroll
      for (int nd = 0; nd < 8; ++nd)
        o[rb + nd * 16 + lo] = (bf16_t)(of[mi][nd][r] * inv);
    }
}

// LayerNorm: one block per row of 1024 f32 -> bf16
__global__ __launch_bounds__(256)
void ln_kernel(const float* __restrict__ x, bf16_t* __restrict__ y,
               const float* __restrict__ w, const float* __restrict__ b)
{
  const long row = blockIdx.x;
  const float4 v = reinterpret_cast<const float4*>(x + row * ND)[threadIdx.x];
  float s  = v.x + v.y + v.z + v.w;
  float ss = v.x * v.x + v.y * v.y + v.z * v.z + v.w * v.w;
#pragma unroll
  for (int off = 32; off; off >>= 1) { s += __shfl_down(s, off); ss += __shfl_down(ss, off); }
  __shared__ float sh[8];
  if ((threadIdx.x & 63) == 0) { sh[threadIdx.x >> 6] = s; sh[4 + (threadIdx.x >> 6)] = ss; }
  __syncthreads();
  const float tot  = sh[0] + sh[1] + sh[2] + sh[3];
  const float tot2 = sh[4] + sh[5] + sh[6] + sh[7];
  const float mean = tot * (1.0f / ND);
  const float var  = tot2 * (1.0f / ND) - mean * mean;
  const float rstd = rsqrtf(var + 1e-5f);
  const int i0 = threadIdx.x * 4;
  const float vv[4] = {v.x, v.y, v.z, v.w};
  bf16x4 o;
#pragma unroll
  for (int j = 0; j < 4; ++j)
    o[j] = (bf16_t)((vv[j] - mean) * rstd * w[i0 + j] + b[i0 + j]);
  reinterpret_cast<bf16x4*>(y + row * ND)[threadIdx.x] = o;
}

// pre-scaled rope table: rtab[s*64+i] = (cos, sin)(s*f_i) * 128^-0.25
__global__ __launch_bounds__(256)
void rtab_kernel(float2* __restrict__ tab)
{
  const int idx = blockIdx.x * 256 + threadIdx.x;   // 65536
  const int s = idx >> 6, i = idx & 63;
  const float freq = __expf((float)i * -0.14391156831212787f);  // 10000^(-2i/128)
  float sn, cs;
  sincosf((float)s * freq, &sn, &cs);
  const float sc = 0.29730177875068026f;
  tab[idx] = make_float2(cs * sc, sn * sc);
}

// im2col conv1: A1[(b*2048+t), i*3+kk] = x[b, i, 2t+kk-1] (pad 1), f32->bf16
__global__ __launch_bounds__(256)
void im2col1_kernel(const float* __restrict__ x, bf16_t* __restrict__ a)
{
  const long idx = (long)blockIdx.x * 256 + threadIdx.x;
  if (idx >= (long)NB * NT1 * 384) return;
  const int  k = (int)(idx % 384);
  const long m = idx / 384;
  const int i = k / 3, kk = k - 3 * i;
  const int t = (int)(m & (NT1 - 1));
  const int b = (int)(m >> 11);
  const int tt = 2 * t + kk - 1;
  float v = 0.0f;
  if (tt >= 0 && tt < NT) v = x[((long)b * 128 + i) * NT + tt];
  a[idx] = (bf16_t)v;
}

// im2col conv2: A2[(b*1024+t), i*3+kk] = h1[b, 2t+kk-1, i] (pad 1)
__global__ __launch_bounds__(256)
void im2col2_kernel(const bf16_t* __restrict__ h1, bf16_t* __restrict__ a)
{
  const long idx = (long)blockIdx.x * 256 + threadIdx.x;
  if (idx >= (long)NB * NS * 3072) return;
  const int  k = (int)(idx % 3072);
  const long m = idx / 3072;
  const int i = k / 3, kk = k - 3 * i;
  const int t = (int)(m & (NS - 1));
  const int b = (int)(m >> 10);
  const int tt = 2 * t + kk - 1;
  bf16_t v = (bf16_t)0.0f;
  if (tt >= 0 && tt < NT1) v = h1[((long)b * NT1 + tt) * ND + i];
  a[idx] = v;
}

__global__ void ylen_kernel(const int* __restrict__ xlen, float* __restrict__ ylen)
{
  const int b = threadIdx.x;
  if (b < NB) {
    const int y1 = (xlen[b] + 1) >> 1;
    ylen[b] = (float)((y1 + 1) >> 1);
  }
}

__global__ __launch_bounds__(256)
void cvt_kernel(const float* __restrict__ in, bf16_t* __restrict__ out, long n)
{
  const long i = ((long)blockIdx.x * 256 + threadIdx.x) * 4;
  if (i >= n) return;
  const float4 v = *reinterpret_cast<const float4*>(in + i);
  bf16x4 o;
  o[0] = (bf16_t)v.x; o[1] = (bf16_t)v.y; o[2] = (bf16_t)v.z; o[3] = (bf16_t)v.w;
  *reinterpret_cast<bf16x4*>(out + i) = o;
}

// three 1M-element f32 arrays -> one contiguous 3M bf16 region
__global__ __launch_bounds__(256)
void cvt3_kernel(const float* __restrict__ a, const float* __restrict__ b,
                 const float* __restrict__ c, bf16_t* __restrict__ out)
{
  const long i = ((long)blockIdx.x * 256 + threadIdx.x) * 4;
  const float* src; long j;
  if (i < 1048576)      { src = a; j = i; }
  else if (i < 2097152) { src = b; j = i - 1048576; }
  else                  { src = c; j = i - 2097152; }
  const float4 v = *reinterpret_cast<const float4*>(src + j);
  bf16x4 o;
  o[0] = (bf16_t)v.x; o[1] = (bf16_t)v.y; o[2] = (bf16_t)v.z; o[3] = (bf16_t)v.w;
  *reinterpret_cast<bf16x4*>(out + i) = o;
}

// two 4M-element f32 arrays -> one contiguous 8M bf16 region
__global__ __launch_bounds__(256)
void cvt2_kernel(const float* __restrict__ a, const float* __restrict__ b,
                 bf16_t* __restrict__ out)
{
  const long i = ((long)blockIdx.x * 256 + threadIdx.x) * 4;
  const float* src; long j;
  if (i < 4194304) { src = a; j = i; }
  else             { src = b; j = i - 4194304; }
  const float4 v = *reinterpret_cast<const float4*>(src + j);
  bf16x4 o;
  o[0] = (bf16_t)v.x; o[1] = (bf16_t)v.y; o[2] = (bf16_t)v.z; o[3] = (bf16_t)v.w;
  *reinterpret_cast<bf16x4*>(out + i) = o;
}

extern "C" void kernel_launch(void* const* d_in, const int* in_sizes, int n_in,
                              void* d_out, int out_size, void* d_ws, size_t ws_size,
                              hipStream_t stream)
{
  const float* x         = (const float*)d_in[0];
  const int*   x_len     = (const int*)  d_in[1];
  const float* conv1_w   = (const float*)d_in[2];
  const float* conv1_b   = (const float*)d_in[3];
  const float* conv2_w   = (const float*)d_in[4];
  const float* conv2_b   = (const float*)d_in[5];
  const float* attn_ln_w = (const float*)d_in[6];
  const float* attn_ln_b = (const float*)d_in[7];
  const float* q_w   = (const float*)d_in[8];
  const float* q_b   = (const float*)d_in[9];
  const float* k_w   = (const float*)d_in[10];
  const float* v_w   = (const float*)d_in[11];
  const float* v_b   = (const float*)d_in[12];
  const float* out_w = (const float*)d_in[13];
  const float* out_b = (const float*)d_in[14];
  const float* mlp_ln_w = (const float*)d_in[15];
  const float* mlp_ln_b = (const float*)d_in[16];
  const float* mlp1_w = (const float*)d_in[17];
  const float* mlp1_b = (const float*)d_in[18];
  const float* mlp2_w = (const float*)d_in[19];
  const float* mlp2_b = (const float*)d_in[20];
  float* outp = (float*)d_out;
  (void)in_sizes; (void)n_in; (void)out_size;

  const long MB = 1024L * 1024;
  char* ws = (char*)d_ws;
  size_t off = 0;
  auto alloc = [&](size_t bytes) -> char* {
    char* p = ws + off;
    off += (bytes + 255) & ~(size_t)255;
    return p;
  };
  bf16_t* ybuf  = (bf16_t*)alloc(16 * MB);       //  16 MB | a1(conv)
  bf16_t* qbuf  = (bf16_t*)alloc(16 * MB);       //  16 MB | h1[0:16] | Q then O
  char*   R     = alloc(64 * MB);                //  64 MB | h1[16:32]+a2 | kbuf | hid
  char*   wA    = alloc(24 * MB);                //  24 MB | weights/vt/rtab
  const size_t required = off;

  // conv-phase aliases
  bf16_t* a1  = ybuf;                            // 12 MB
  bf16_t* h1  = qbuf;                            // 32 MB (qbuf + R[0:16])
  bf16_t* a2  = (bf16_t*)(R + 16 * MB);          // 48 MB
  bf16_t* c2w = (bf16_t*)wA;                     //  6 MB
  bf16_t* c1w = (bf16_t*)(wA + 8 * MB);          // 0.75 MB
  // persistent
  float2* rtab = (float2*)(wA + 6 * MB);         // 512 KB at [6:6.5], kept
  // layer-phase aliases
  bf16_t* wqkv = (bf16_t*)wA;                    // [0:6]
  bf16_t* vt   = (bf16_t*)(wA + 8 * MB);         // [8:24] during attention
  bf16_t* wo   = (bf16_t*)(wA + 16 * MB);        // [16:18] after flash
  bf16_t* w1b  = (bf16_t*)(wA + 8 * MB);         // [8:16] after attn-out
  bf16_t* w2b  = (bf16_t*)(wA + 16 * MB);        // [16:24]
  bf16_t* kbuf = (bf16_t*)R;                     // [0:16] during attention
  bf16_t* hid  = (bf16_t*)R;                     // 64 MB during MLP

  if (required > ws_size) {
    ylen_kernel<<<dim3(1), 64, 0, stream>>>(x_len, outp + 8L * 1024 * 1024);
    return;
  }

  auto cvt = [&](const float* in, bf16_t* o, long n) {
    cvt_kernel<<<dim3((unsigned)(n / 1024)), 256, 0, stream>>>(in, o, n);
  };

  rtab_kernel<<<dim3(256), 256, 0, stream>>>(rtab);

  // ---- conv stem ----
  cvt(conv1_w, c1w, 1024L * 384);
  cvt(conv2_w, c2w, 1024L * 3072);
  im2col1_kernel<<<dim3((unsigned)((16384L * 384) / 256)), 256, 0, stream>>>(x, a1);
  gemm_bt<EPI_GELU_BF16><<<dim3(64, 4), 512, 0, stream>>>(
      a1, 384, c1w, 384, h1, 1024, conv1_b, nullptr, 384, 1,
      nullptr, nullptr, nullptr, nullptr);
  im2col2_kernel<<<dim3((unsigned)((8192L * 3072) / 256)), 256, 0, stream>>>(h1, a2);
  gemm_bt<EPI_GELU_F32><<<dim3(32, 4), 512, 0, stream>>>(
      a2, 3072, c2w, 3072, outp /*carry*/, 1024, conv2_b, nullptr, 3072, 1,
      nullptr, nullptr, nullptr, nullptr);

  float* carry = outp;  // f32 residual stream lives in d_out

  for (int l = 0; l < 6; ++l) {
    cvt3_kernel<<<dim3(3072), 256, 0, stream>>>(
        q_w + (long)l * 1048576, k_w + (long)l * 1048576, v_w + (long)l * 1048576, wqkv);

    ln_kernel<<<dim3(8192), 256, 0, stream>>>(carry, ybuf, attn_ln_w + l * 1024, attn_ln_b + l * 1024);

    // fused QKV projection + rope/scale + V-transpose (N=3072)
    gemm_bt<EPI_QKV><<<dim3(32, 12), 512, 0, stream>>>(
        ybuf, 1024, wqkv, 1024, qbuf, 1024,
        q_b + l * 1024, nullptr, 1024, 1, kbuf, vt, v_b + l * 1024, rtab);

    // flash attention: O overwrites Q in place
    flash_kernel<<<dim3(8, 64), 256, 0, stream>>>(qbuf, kbuf, vt, qbuf, x_len);

    // carry += O @ ow^T + ob
    cvt(out_w + (long)l * 1048576, wo, 1048576);
    gemm_bt<EPI_RES_F32><<<dim3(32, 4), 512, 0, stream>>>(
        qbuf, 1024, wo, 1024, carry, 1024,
        out_b + l * 1024, carry, 1024, 1, nullptr, nullptr, nullptr, nullptr);

    cvt2_kernel<<<dim3(8192), 256, 0, stream>>>(
        mlp1_w + (long)l * 4194304, mlp2_w + (long)l * 4194304, w1b);

    ln_kernel<<<dim3(8192), 256, 0, stream>>>(carry, ybuf, mlp_ln_w + l * 1024, mlp_ln_b + l * 1024);

    gemm_bt<EPI_GELU_BF16><<<dim3(32, 16), 512, 0, stream>>>(
        ybuf, 1024, w1b, 1024, hid, 4096,
        mlp1_b + (long)l * 4096, nullptr, 1024, 1, nullptr, nullptr, nullptr, nullptr);
    gemm_bt<EPI_RES_F32><<<dim3(32, 4), 512, 0, stream>>>(
        hid, 4096, w2b, 4096, carry, 1024,
        mlp2_b + l * 1024, carry, 4096, 1, nullptr, nullptr, nullptr, nullptr);
  }

  ylen_kernel<<<dim3(1), 64, 0, stream>>>(x_len, outp + 8L * 1024 * 1024);
}

// Round 7
// 3173.481 us; speedup vs baseline: 1.3030x; 1.3030x over previous
//
#include <hip/hip_runtime.h>
#include <hip/hip_bf16.h>
#include <cstdint>
#include <cstddef>

// ---------------------------------------------------------------------------
// AudioEncoder (Whisper-style) forward for MI355X.
// B=8, T=4096, n_mels=128, D=1024, H=8 heads (hd=128), F=4096, L=6, S=1024.
// GEMMs: 128x128 tile, 4 waves, BK=32, TRIPLE-buffered LDS with counted
// vmcnt(4) + raw barrier (one barrier per K-step, loads span barriers),
// read-side XOR swizzle (2-way max). Fast sigmoid-form gelu.
// Attention: flash kernel with LDS-staged double-buffered K/V (unchanged).
// ---------------------------------------------------------------------------

typedef __bf16 bf16_t;
typedef __bf16 bf16x8 __attribute__((ext_vector_type(8)));
typedef __bf16 bf16x4 __attribute__((ext_vector_type(4)));
typedef float  floatx4 __attribute__((ext_vector_type(4)));

#define NB   8
#define NS   1024
#define ND   1024
#define NT   4096
#define NT1  2048

#define MFMA16(a, b, c) __builtin_amdgcn_mfma_f32_16x16x32_bf16(a, b, c, 0, 0, 0)

#define SBAR() do { __builtin_amdgcn_sched_barrier(0); \
                    __builtin_amdgcn_s_barrier();      \
                    __builtin_amdgcn_sched_barrier(0); } while (0)

__device__ __forceinline__ float gelu_f(float x) {
  // tanh-form gelu via sigmoid: 0.5x(1+tanh(z)) = x*sigmoid(2z); |err|<~3e-3
  const float t = 1.5957691216057308f * (x + 0.044715f * x * x * x);
  return x / (1.0f + __expf(-t));
}

__device__ __forceinline__ void gload16(const void* g, void* l) {
  __builtin_amdgcn_global_load_lds(
      (__attribute__((address_space(1))) void*)(const_cast<void*>(g)),
      (__attribute__((address_space(3))) void*)l, 16, 0, 0);
}

enum { EPI_BF16 = 0, EPI_GELU_BF16 = 2, EPI_GELU_F32 = 3, EPI_RES_F32 = 4, EPI_QKV = 5 };

// C = A (M,K) @ B^T, B stored (N,K) row-major. 128x128 tile, 4 waves, each a
// 64x64 quadrant of 4x4 16x16x32-bf16 MFMA frags. 3-buffer LDS pipeline:
// stage(s+2) issued first, ds_read+MFMA on buf s, then counted vmcnt(4)
// (tile s+1 landed, s+2 still in flight) + raw s_barrier. LDS slot-swizzled
// (slot ^= (row>>1)&3): inverse-swizzled global source, same XOR on reads.
template<int EPI>
__global__ __launch_bounds__(256)
void gemm_bt(const bf16_t* __restrict__ A, long lda,
             const bf16_t* __restrict__ Bm, long ldb,
             void* Cv, long ldc,
             const float* __restrict__ bias, const float* res,
             int K, int swz,
             bf16_t* out2, bf16_t* out3, const float* __restrict__ bias2,
             const float2* __restrict__ rtab)
{
  __shared__ bf16_t sA[3][4096];   // 3 x 8KB per matrix (48KB total)
  __shared__ bf16_t sB[3][4096];
  const int tid  = threadIdx.x;
  const int w    = tid >> 6;
  const int lane = tid & 63;
  const int lo = lane & 15, g = lane >> 4;
  const int wr = w >> 1, wc = w & 1;

  int bx = blockIdx.x, by = blockIdx.y;
  if (swz) {               // bijective XCD-chunked remap (grid size % 8 == 0)
    const int gx = gridDim.x;
    const int n  = gx * gridDim.y;
    int id = bx + by * gx;
    id = (id & 7) * (n >> 3) + (id >> 3);
    bx = id % gx; by = id / gx;
  }
  const int m0 = bx * 128, n0 = by * 128;
  const int NTK = K >> 5;

  const int lrow = lane >> 2;                         // LDS row within segment
  const int lcol = 8 * ((lane & 3) ^ ((lane >> 3) & 3));  // inv-swizzled source

  auto stage = [&](int t) {
    if (t >= NTK) return;
    const int kb = t << 5;
    bf16_t* dA = &sA[t % 3][0];
    bf16_t* dB = &sB[t % 3][0];
#pragma unroll
    for (int j = 0; j < 2; ++j) {
      const int seg = w * 2 + j;       // 8 segments x 16 rows x 64B
      gload16(A  + (long)(m0 + seg * 16 + lrow) * lda + kb + lcol, dA + seg * 512);
      gload16(Bm + (long)(n0 + seg * 16 + lrow) * ldb + kb + lcol, dB + seg * 512);
    }
  };

  const int rslot = 16 * (g ^ ((lo >> 1) & 3));   // read-side slot XOR (bytes)

  floatx4 acc[4][4] = {};

  stage(0); stage(1);
  asm volatile("s_waitcnt vmcnt(4)" ::: "memory");   // tile0 landed
  SBAR();

#pragma unroll 1
  for (int s = 0; s < NTK; ++s) {
    stage(s + 2);                                    // issue-early prefetch
    const bf16_t* bufA = &sA[s % 3][0];
    const bf16_t* bufB = &sB[s % 3][0];
    bf16x8 av[4], bv[4];
#pragma unroll
    for (int i = 0; i < 4; ++i) {
      av[i] = *(const bf16x8*)((const char*)(bufA + (wr * 64 + i * 16 + lo) * 32) + rslot);
      bv[i] = *(const bf16x8*)((const char*)(bufB + (wc * 64 + i * 16 + lo) * 32) + rslot);
    }
#pragma unroll
    for (int mi = 0; mi < 4; ++mi)
#pragma unroll
      for (int ni = 0; ni < 4; ++ni)
        acc[mi][ni] = MFMA16(av[mi], bv[ni], acc[mi][ni]);
    if (s + 2 < NTK) { asm volatile("s_waitcnt vmcnt(4)" ::: "memory"); }
    else             { asm volatile("s_waitcnt vmcnt(0)" ::: "memory"); }
    SBAR();
  }

  // ---- epilogue ----
  if constexpr (EPI == EPI_QKV) {
    const int sect = n0 >> 10;        // 0=Q 1=K 2=V
#pragma unroll
    for (int ni = 0; ni < 4; ++ni) {
      const int col = n0 + wc * 64 + ni * 16 + lo;
      const int c10 = col & 1023;
      float bvs = 0.0f;
      if (sect == 0) bvs = bias[c10];
      else if (sect == 2) bvs = bias2[c10];
#pragma unroll
      for (int mi = 0; mi < 4; ++mi) {
#pragma unroll
        for (int r = 0; r < 4; ++r) {
          const int row = m0 + wr * 64 + mi * 16 + g * 4 + r;
          const int s = row & 1023;
          float val = acc[mi][ni][r] + bvs;
          if (sect < 2) {             // rope + scale (table pre-scaled)
            const float2 t = rtab[(s << 6) + ((col & 127) >> 1)];
            const float p = __shfl_xor(val, 1);
            val = val * t.x + p * ((col & 1) ? t.y : -t.y);
            bf16_t* dst = sect ? out2 : (bf16_t*)Cv;
            dst[(long)row * 1024 + c10] = (bf16_t)val;
          } else {                    // vt[b][h*128+d][s]
            out3[((long)(row >> 10) << 20) + ((long)(col - 2048) << 10) + s] = (bf16_t)val;
          }
        }
      }
    }
    return;
  }

#pragma unroll
  for (int ni = 0; ni < 4; ++ni) {
    const int col = n0 + wc * 64 + ni * 16 + lo;
    const float bvs = bias ? bias[col] : 0.0f;
#pragma unroll
    for (int mi = 0; mi < 4; ++mi) {
#pragma unroll
      for (int r = 0; r < 4; ++r) {
        const int row = m0 + wr * 64 + mi * 16 + g * 4 + r;
        float v = acc[mi][ni][r] + bvs;
        if constexpr (EPI == EPI_BF16) {
          ((bf16_t*)Cv)[(long)row * ldc + col] = (bf16_t)v;
        } else if constexpr (EPI == EPI_GELU_BF16) {
          ((bf16_t*)Cv)[(long)row * ldc + col] = (bf16_t)gelu_f(v);
        } else if constexpr (EPI == EPI_GELU_F32) {
          ((float*)Cv)[(long)row * ldc + col] = gelu_f(v);
        } else {  // EPI_RES_F32
          const long idx = (long)row * ldc + col;
          ((float*)Cv)[idx] = res[idx] + v;
        }
      }
    }
  }
}

// ---------------------------------------------------------------------------
// Flash attention (unchanged): grid (S/128, B*H), 4 waves/block.
// ---------------------------------------------------------------------------
__global__ __launch_bounds__(256)
void flash_kernel(const bf16_t* __restrict__ q, const bf16_t* __restrict__ k,
                  const bf16_t* __restrict__ vt, bf16_t* __restrict__ o,
                  const int* __restrict__ xlen)
{
  __shared__ bf16_t sK[2][4096];   // [kv=64][d=128], rows swizzled
  __shared__ bf16_t sV[2][4096];   // [d=128][kv=64], rows swizzled
  __shared__ bf16_t sP[4][2048];   // per-wave [q=32][kv=64], swizzled
  const int tid = threadIdx.x, w = tid >> 6, lane = tid & 63;
  const int lo = lane & 15, g = lane >> 4;
  const int bh = blockIdx.y, b = bh >> 3, h = bh & 7;
  const int q0 = blockIdx.x * 128 + w * 32;
  const int nv  = xlen[b] >> 2;
  const int nkt = (nv + 63) >> 6;
  const long base = (long)b * 1048576 + (long)h * 128;
  const bf16_t* Qp = q + base;
  const bf16_t* Kp = k + base;
  const bf16_t* Vp = vt + (long)b * 1048576 + ((long)h << 17);

  auto stageKV = [&](int kt, int buf) {
    const int kv0 = kt << 6;
#pragma unroll
    for (int j = 0; j < 4; ++j) {
      const int seg = (w << 2) + j;
      {
        const int row = (seg << 2) + (lane >> 4);
        const int col = ((lane & 15) << 3) ^ ((row & 7) << 3);
        gload16(Kp + (long)(kv0 + row) * 1024 + col, &sK[buf][seg * 512]);
      }
      {
        const int row = (seg << 3) + (lane >> 3);
        const int col = ((lane & 7) << 3) ^ ((row & 7) << 3);
        gload16(Vp + (long)row * 1024 + kv0 + col, &sV[buf][seg * 512]);
      }
    }
  };

  bf16x8 qf[2][4];
#pragma unroll
  for (int mi = 0; mi < 2; ++mi)
#pragma unroll
    for (int ks = 0; ks < 4; ++ks)
      qf[mi][ks] = *reinterpret_cast<const bf16x8*>(
          Qp + (long)(q0 + mi * 16 + lo) * 1024 + ks * 32 + g * 8);

  floatx4 of[2][8] = {};
  float m[2][4], l[2][4];
#pragma unroll
  for (int mi = 0; mi < 2; ++mi)
#pragma unroll
    for (int r = 0; r < 4; ++r) { m[mi][r] = -1e30f; l[mi][r] = 0.0f; }

  const char* kbase = (const char*)&sK[0][0];
  const char* vbase = (const char*)&sV[0][0];
  char* pbase = (char*)&sP[w][0];
  const int swzL = (lo & 7) << 4;

  stageKV(0, 0);
  __syncthreads();
  int cur = 0;
#pragma unroll 1
  for (int kt = 0; kt < nkt; ++kt) {
    const int kv0 = kt << 6;
    if (kt + 1 < nkt) stageKV(kt + 1, cur ^ 1);

    floatx4 s[2][4] = {};
#pragma unroll
    for (int ni = 0; ni < 4; ++ni) {
#pragma unroll
      for (int ks = 0; ks < 4; ++ks) {
        const bf16x8 bv = *reinterpret_cast<const bf16x8*>(
            kbase + cur * 8192 + (ni * 16 + lo) * 256 + ((ks * 64 + (g << 4)) ^ swzL));
        s[0][ni] = MFMA16(qf[0][ks], bv, s[0][ni]);
        s[1][ni] = MFMA16(qf[1][ks], bv, s[1][ni]);
      }
    }

#pragma unroll
    for (int mi = 0; mi < 2; ++mi) {
#pragma unroll
      for (int r = 0; r < 4; ++r) {
        float vv[4]; float pm = -1e30f;
#pragma unroll
        for (int ni = 0; ni < 4; ++ni) {
          float val = s[mi][ni][r];
          if (kv0 + ni * 16 + lo >= nv) val = -1e30f;
          vv[ni] = val; pm = fmaxf(pm, val);
        }
        pm = fmaxf(pm, __shfl_xor(pm, 1)); pm = fmaxf(pm, __shfl_xor(pm, 2));
        pm = fmaxf(pm, __shfl_xor(pm, 4)); pm = fmaxf(pm, __shfl_xor(pm, 8));
        const float mo = m[mi][r];
        const float mn = fmaxf(mo, pm);
        const float sc = __expf(mo - mn);
        const int qrow = mi * 16 + g * 4 + r;
        const int sw = (qrow & 7) << 4;
        float ss = 0.0f;
#pragma unroll
        for (int ni = 0; ni < 4; ++ni) {
          const float p = __expf(vv[ni] - mn);
          ss += p;
          *(bf16_t*)(pbase + qrow * 128 + (((ni << 5) + (lo << 1)) ^ sw)) = (bf16_t)p;
        }
        ss += __shfl_xor(ss, 1); ss += __shfl_xor(ss, 2);
        ss += __shfl_xor(ss, 4); ss += __shfl_xor(ss, 8);
        l[mi][r] = l[mi][r] * sc + ss;
        m[mi][r] = mn;
#pragma unroll
        for (int nd = 0; nd < 8; ++nd) of[mi][nd][r] *= sc;
      }
    }

    asm volatile("s_waitcnt lgkmcnt(0)" ::: "memory");
    __builtin_amdgcn_sched_barrier(0);

#pragma unroll
    for (int ks = 0; ks < 2; ++ks) {
      bf16x8 av0 = *reinterpret_cast<const bf16x8*>(
          pbase + (0 * 16 + lo) * 128 + (((ks << 6) + (g << 4)) ^ swzL));
      bf16x8 av1 = *reinterpret_cast<const bf16x8*>(
          pbase + (1 * 16 + lo) * 128 + (((ks << 6) + (g << 4)) ^ swzL));
#pragma unroll
      for (int nd = 0; nd < 8; ++nd) {
        const bf16x8 bv = *reinterpret_cast<const bf16x8*>(
            vbase + cur * 8192 + (nd * 16 + lo) * 128 + (((ks << 6) + (g << 4)) ^ swzL));
        of[0][nd] = MFMA16(av0, bv, of[0][nd]);
        of[1][nd] = MFMA16(av1, bv, of[1][nd]);
      }
    }
    __syncthreads();
    cur ^= 1;
  }

#pragma unroll
  for (int mi = 0; mi < 2; ++mi)
#pragma unroll
    for (int r = 0; r < 4; ++r) {
      const float inv = 1.0f / l[mi][r];
      const long rb = base + (long)(q0 + mi * 16 + g * 4 + r) * 1024;
#pragma unroll
      for (int nd = 0; nd < 8; ++nd)
        o[rb + nd * 16 + lo] = (bf16_t)(of[mi][nd][r] * inv);
    }
}

// LayerNorm: one block per row of 1024 f32 -> bf16
__global__ __launch_bounds__(256)
void ln_kernel(const float* __restrict__ x, bf16_t* __restrict__ y,
               const float* __restrict__ w, const float* __restrict__ b)
{
  const long row = blockIdx.x;
  const float4 v = reinterpret_cast<const float4*>(x + row * ND)[threadIdx.x];
  float s  = v.x + v.y + v.z + v.w;
  float ss = v.x * v.x + v.y * v.y + v.z * v.z + v.w * v.w;
#pragma unroll
  for (int off = 32; off; off >>= 1) { s += __shfl_down(s, off); ss += __shfl_down(ss, off); }
  __shared__ float sh[8];
  if ((threadIdx.x & 63) == 0) { sh[threadIdx.x >> 6] = s; sh[4 + (threadIdx.x >> 6)] = ss; }
  __syncthreads();
  const float tot  = sh[0] + sh[1] + sh[2] + sh[3];
  const float tot2 = sh[4] + sh[5] + sh[6] + sh[7];
  const float mean = tot * (1.0f / ND);
  const float var  = tot2 * (1.0f / ND) - mean * mean;
  const float rstd = rsqrtf(var + 1e-5f);
  const int i0 = threadIdx.x * 4;
  const float vv[4] = {v.x, v.y, v.z, v.w};
  bf16x4 o;
#pragma unroll
  for (int j = 0; j < 4; ++j)
    o[j] = (bf16_t)((vv[j] - mean) * rstd * w[i0 + j] + b[i0 + j]);
  reinterpret_cast<bf16x4*>(y + row * ND)[threadIdx.x] = o;
}

// pre-scaled rope table: rtab[s*64+i] = (cos, sin)(s*f_i) * 128^-0.25
__global__ __launch_bounds__(256)
void rtab_kernel(float2* __restrict__ tab)
{
  const int idx = blockIdx.x * 256 + threadIdx.x;   // 65536
  const int s = idx >> 6, i = idx & 63;
  const float freq = __expf((float)i * -0.14391156831212787f);  // 10000^(-2i/128)
  float sn, cs;
  sincosf((float)s * freq, &sn, &cs);
  const float sc = 0.29730177875068026f;
  tab[idx] = make_float2(cs * sc, sn * sc);
}

// im2col conv1: A1[(b*2048+t), i*3+kk] = x[b, i, 2t+kk-1] (pad 1), f32->bf16
__global__ __launch_bounds__(256)
void im2col1_kernel(const float* __restrict__ x, bf16_t* __restrict__ a)
{
  const long idx = (long)blockIdx.x * 256 + threadIdx.x;
  if (idx >= (long)NB * NT1 * 384) return;
  const int  k = (int)(idx % 384);
  const long m = idx / 384;
  const int i = k / 3, kk = k - 3 * i;
  const int t = (int)(m & (NT1 - 1));
  const int b = (int)(m >> 11);
  const int tt = 2 * t + kk - 1;
  float v = 0.0f;
  if (tt >= 0 && tt < NT) v = x[((long)b * 128 + i) * NT + tt];
  a[idx] = (bf16_t)v;
}

// im2col conv2: A2[(b*1024+t), i*3+kk] = h1[b, 2t+kk-1, i] (pad 1)
__global__ __launch_bounds__(256)
void im2col2_kernel(const bf16_t* __restrict__ h1, bf16_t* __restrict__ a)
{
  const long idx = (long)blockIdx.x * 256 + threadIdx.x;
  if (idx >= (long)NB * NS * 3072) return;
  const int  k = (int)(idx % 3072);
  const long m = idx / 3072;
  const int i = k / 3, kk = k - 3 * i;
  const int t = (int)(m & (NS - 1));
  const int b = (int)(m >> 10);
  const int tt = 2 * t + kk - 1;
  bf16_t v = (bf16_t)0.0f;
  if (tt >= 0 && tt < NT1) v = h1[((long)b * NT1 + tt) * ND + i];
  a[idx] = v;
}

__global__ void ylen_kernel(const int* __restrict__ xlen, float* __restrict__ ylen)
{
  const int b = threadIdx.x;
  if (b < NB) {
    const int y1 = (xlen[b] + 1) >> 1;
    ylen[b] = (float)((y1 + 1) >> 1);
  }
}

__global__ __launch_bounds__(256)
void cvt_kernel(const float* __restrict__ in, bf16_t* __restrict__ out, long n)
{
  const long i = ((long)blockIdx.x * 256 + threadIdx.x) * 4;
  if (i >= n) return;
  const float4 v = *reinterpret_cast<const float4*>(in + i);
  bf16x4 o;
  o[0] = (bf16_t)v.x; o[1] = (bf16_t)v.y; o[2] = (bf16_t)v.z; o[3] = (bf16_t)v.w;
  *reinterpret_cast<bf16x4*>(out + i) = o;
}

// three 1M-element f32 arrays -> one contiguous 3M bf16 region
__global__ __launch_bounds__(256)
void cvt3_kernel(const float* __restrict__ a, const float* __restrict__ b,
                 const float* __restrict__ c, bf16_t* __restrict__ out)
{
  const long i = ((long)blockIdx.x * 256 + threadIdx.x) * 4;
  const float* src; long j;
  if (i < 1048576)      { src = a; j = i; }
  else if (i < 2097152) { src = b; j = i - 1048576; }
  else                  { src = c; j = i - 2097152; }
  const float4 v = *reinterpret_cast<const float4*>(src + j);
  bf16x4 o;
  o[0] = (bf16_t)v.x; o[1] = (bf16_t)v.y; o[2] = (bf16_t)v.z; o[3] = (bf16_t)v.w;
  *reinterpret_cast<bf16x4*>(out + i) = o;
}

// two 4M-element f32 arrays -> one contiguous 8M bf16 region
__global__ __launch_bounds__(256)
void cvt2_kernel(const float* __restrict__ a, const float* __restrict__ b,
                 bf16_t* __restrict__ out)
{
  const long i = ((long)blockIdx.x * 256 + threadIdx.x) * 4;
  const float* src; long j;
  if (i < 4194304) { src = a; j = i; }
  else             { src = b; j = i - 4194304; }
  const float4 v = *reinterpret_cast<const float4*>(src + j);
  bf16x4 o;
  o[0] = (bf16_t)v.x; o[1] = (bf16_t)v.y; o[2] = (bf16_t)v.z; o[3] = (bf16_t)v.w;
  *reinterpret_cast<bf16x4*>(out + i) = o;
}

extern "C" void kernel_launch(void* const* d_in, const int* in_sizes, int n_in,
                              void* d_out, int out_size, void* d_ws, size_t ws_size,
                              hipStream_t stream)
{
  const float* x         = (const float*)d_in[0];
  const int*   x_len     = (const int*)  d_in[1];
  const float* conv1_w   = (const float*)d_in[2];
  const float* conv1_b   = (const float*)d_in[3];
  const float* conv2_w   = (const float*)d_in[4];
  const float* conv2_b   = (const float*)d_in[5];
  const float* attn_ln_w = (const float*)d_in[6];
  const float* attn_ln_b = (const float*)d_in[7];
  const float* q_w   = (const float*)d_in[8];
  const float* q_b   = (const float*)d_in[9];
  const float* k_w   = (const float*)d_in[10];
  const float* v_w   = (const float*)d_in[11];
  const float* v_b   = (const float*)d_in[12];
  const float* out_w = (const float*)d_in[13];
  const float* out_b = (const float*)d_in[14];
  const float* mlp_ln_w = (const float*)d_in[15];
  const float* mlp_ln_b = (const float*)d_in[16];
  const float* mlp1_w = (const float*)d_in[17];
  const float* mlp1_b = (const float*)d_in[18];
  const float* mlp2_w = (const float*)d_in[19];
  const float* mlp2_b = (const float*)d_in[20];
  float* outp = (float*)d_out;
  (void)in_sizes; (void)n_in; (void)out_size;

  const long MB = 1024L * 1024;
  char* ws = (char*)d_ws;
  size_t off = 0;
  auto alloc = [&](size_t bytes) -> char* {
    char* p = ws + off;
    off += (bytes + 255) & ~(size_t)255;
    return p;
  };
  bf16_t* ybuf  = (bf16_t*)alloc(16 * MB);       //  16 MB | a1(conv)
  bf16_t* qbuf  = (bf16_t*)alloc(16 * MB);       //  16 MB | h1[0:16] | Q then O
  char*   R     = alloc(64 * MB);                //  64 MB | h1[16:32]+a2 | kbuf | hid
  char*   wA    = alloc(24 * MB);                //  24 MB | weights/vt/rtab
  const size_t required = off;

  // conv-phase aliases
  bf16_t* a1  = ybuf;                            // 12 MB
  bf16_t* h1  = qbuf;                            // 32 MB (qbuf + R[0:16])
  bf16_t* a2  = (bf16_t*)(R + 16 * MB);          // 48 MB
  bf16_t* c2w = (bf16_t*)wA;                     //  6 MB
  bf16_t* c1w = (bf16_t*)(wA + 8 * MB);          // 0.75 MB
  // persistent
  float2* rtab = (float2*)(wA + 6 * MB);         // 512 KB at [6:6.5], kept
  // layer-phase aliases
  bf16_t* wqkv = (bf16_t*)wA;                    // [0:6]
  bf16_t* vt   = (bf16_t*)(wA + 8 * MB);         // [8:24] during attention
  bf16_t* wo   = (bf16_t*)(wA + 16 * MB);        // [16:18] after flash
  bf16_t* w1b  = (bf16_t*)(wA + 8 * MB);         // [8:16] after attn-out
  bf16_t* w2b  = (bf16_t*)(wA + 16 * MB);        // [16:24]
  bf16_t* kbuf = (bf16_t*)R;                     // [0:16] during attention
  bf16_t* hid  = (bf16_t*)R;                     // 64 MB during MLP

  if (required > ws_size) {
    ylen_kernel<<<dim3(1), 64, 0, stream>>>(x_len, outp + 8L * 1024 * 1024);
    return;
  }

  auto cvt = [&](const float* in, bf16_t* o, long n) {
    cvt_kernel<<<dim3((unsigned)(n / 1024)), 256, 0, stream>>>(in, o, n);
  };

  rtab_kernel<<<dim3(256), 256, 0, stream>>>(rtab);

  // ---- conv stem ----
  cvt(conv1_w, c1w, 1024L * 384);
  cvt(conv2_w, c2w, 1024L * 3072);
  im2col1_kernel<<<dim3((unsigned)((16384L * 384) / 256)), 256, 0, stream>>>(x, a1);
  gemm_bt<EPI_GELU_BF16><<<dim3(128, 8), 256, 0, stream>>>(
      a1, 384, c1w, 384, h1, 1024, conv1_b, nullptr, 384, 1,
      nullptr, nullptr, nullptr, nullptr);
  im2col2_kernel<<<dim3((unsigned)((8192L * 3072) / 256)), 256, 0, stream>>>(h1, a2);
  gemm_bt<EPI_GELU_F32><<<dim3(64, 8), 256, 0, stream>>>(
      a2, 3072, c2w, 3072, outp /*carry*/, 1024, conv2_b, nullptr, 3072, 1,
      nullptr, nullptr, nullptr, nullptr);

  float* carry = outp;  // f32 residual stream lives in d_out

  for (int l = 0; l < 6; ++l) {
    cvt3_kernel<<<dim3(3072), 256, 0, stream>>>(
        q_w + (long)l * 1048576, k_w + (long)l * 1048576, v_w + (long)l * 1048576, wqkv);

    ln_kernel<<<dim3(8192), 256, 0, stream>>>(carry, ybuf, attn_ln_w + l * 1024, attn_ln_b + l * 1024);

    // fused QKV projection + rope/scale + V-transpose (N=3072)
    gemm_bt<EPI_QKV><<<dim3(64, 24), 256, 0, stream>>>(
        ybuf, 1024, wqkv, 1024, qbuf, 1024,
        q_b + l * 1024, nullptr, 1024, 1, kbuf, vt, v_b + l * 1024, rtab);

    // flash attention: O overwrites Q in place
    flash_kernel<<<dim3(8, 64), 256, 0, stream>>>(qbuf, kbuf, vt, qbuf, x_len);

    // carry += O @ ow^T + ob
    cvt(out_w + (long)l * 1048576, wo, 1048576);
    gemm_bt<EPI_RES_F32><<<dim3(64, 8), 256, 0, stream>>>(
        qbuf, 1024, wo, 1024, carry, 1024,
        out_b + l * 1024, carry, 1024, 1, nullptr, nullptr, nullptr, nullptr);

    cvt2_kernel<<<dim3(8192), 256, 0, stream>>>(
        mlp1_w + (long)l * 4194304, mlp2_w + (long)l * 4194304, w1b);

    ln_kernel<<<dim3(8192), 256, 0, stream>>>(carry, ybuf, mlp_ln_w + l * 1024, mlp_ln_b + l * 1024);

    gemm_bt<EPI_GELU_BF16><<<dim3(64, 32), 256, 0, stream>>>(
        ybuf, 1024, w1b, 1024, hid, 4096,
        mlp1_b + (long)l * 4096, nullptr, 1024, 1, nullptr, nullptr, nullptr, nullptr);
    gemm_bt<EPI_RES_F32><<<dim3(64, 8), 256, 0, stream>>>(
        hid, 4096, w2b, 4096, carry, 1024,
        mlp2_b + l * 1024, carry, 4096, 1, nullptr, nullptr, nullptr, nullptr);
  }

  ylen_kernel<<<dim3(1), 64, 0, stream>>>(x_len, outp + 8L * 1024 * 1024);
}

// Round 8
// 3009.820 us; speedup vs baseline: 1.3738x; 1.0544x over previous
//
#include <hip/hip_runtime.h>
#include <hip/hip_bf16.h>
#include <cstdint>
#include <cstddef>

// ---------------------------------------------------------------------------
// AudioEncoder (Whisper-style) forward for MI355X.
// B=8, T=4096, n_mels=128, D=1024, H=8 heads (hd=128), F=4096, L=6, S=1024.
// GEMMs: 128x128 tile, 8 waves (2Mx4N, 512 threads), BK=32, triple-buffered
// LDS with counted vmcnt(2) + raw barrier; read-side XOR swizzle.
// Attention: flash kernel with LDS-staged double-buffered K/V (unchanged).
// ---------------------------------------------------------------------------

typedef __bf16 bf16_t;
typedef __bf16 bf16x8 __attribute__((ext_vector_type(8)));
typedef __bf16 bf16x4 __attribute__((ext_vector_type(4)));
typedef float  floatx4 __attribute__((ext_vector_type(4)));

#define NB   8
#define NS   1024
#define ND   1024
#define NT   4096
#define NT1  2048

#define MFMA16(a, b, c) __builtin_amdgcn_mfma_f32_16x16x32_bf16(a, b, c, 0, 0, 0)

#define SBAR() do { __builtin_amdgcn_sched_barrier(0); \
                    __builtin_amdgcn_s_barrier();      \
                    __builtin_amdgcn_sched_barrier(0); } while (0)

__device__ __forceinline__ float gelu_f(float x) {
  // tanh-form gelu via sigmoid: 0.5x(1+tanh(z)) = x*sigmoid(2z); |err|<~3e-3
  const float t = 1.5957691216057308f * (x + 0.044715f * x * x * x);
  return x / (1.0f + __expf(-t));
}

__device__ __forceinline__ void gload16(const void* g, void* l) {
  __builtin_amdgcn_global_load_lds(
      (__attribute__((address_space(1))) void*)(const_cast<void*>(g)),
      (__attribute__((address_space(3))) void*)l, 16, 0, 0);
}

enum { EPI_BF16 = 0, EPI_GELU_BF16 = 2, EPI_GELU_F32 = 3, EPI_RES_F32 = 4, EPI_QKV = 5 };

// C = A (M,K) @ B^T, B stored (N,K) row-major. 128x128 tile, 8 waves (2Mx4N),
// each wave 64x32 output as acc[4][2] of 16x16x32-bf16 MFMA frags. 3-buffer
// LDS pipeline: stage(s+2) issued first (1 A + 1 B gload per wave), compute
// buf s, counted vmcnt(2) (tile s+1 landed, s+2 in flight) + raw s_barrier.
// LDS slot-swizzled: inverse-swizzled global source, same XOR on reads.
template<int EPI>
__global__ __launch_bounds__(512)
void gemm_bt(const bf16_t* __restrict__ A, long lda,
             const bf16_t* __restrict__ Bm, long ldb,
             void* Cv, long ldc,
             const float* __restrict__ bias, const float* res,
             int K, int swz,
             bf16_t* out2, bf16_t* out3, const float* __restrict__ bias2,
             const float2* __restrict__ rtab)
{
  __shared__ bf16_t sA[3][4096];   // 3 x 8KB per matrix (48KB total)
  __shared__ bf16_t sB[3][4096];
  const int tid  = threadIdx.x;
  const int wid  = tid >> 6;       // 0..7
  const int lane = tid & 63;
  const int lo = lane & 15, g = lane >> 4;
  const int wr = wid >> 2, wc = wid & 3;   // 2M x 4N wave grid

  int bx = blockIdx.x, by = blockIdx.y;
  if (swz) {               // bijective XCD-chunked remap (grid size % 8 == 0)
    const int gx = gridDim.x;
    const int n  = gx * gridDim.y;
    int id = bx + by * gx;
    id = (id & 7) * (n >> 3) + (id >> 3);
    bx = id % gx; by = id / gx;
  }
  const int m0 = bx * 128, n0 = by * 128;
  const int NTK = K >> 5;

  const int lrow = lane >> 2;                         // LDS row within segment
  const int lcol = 8 * ((lane & 3) ^ ((lane >> 3) & 3));  // inv-swizzled source

  auto stage = [&](int t) {
    if (t >= NTK) return;
    const int kb = t << 5;
    bf16_t* dA = &sA[t % 3][0];
    bf16_t* dB = &sB[t % 3][0];
    const int seg = wid;             // 8 segments x 16 rows x 64B each matrix
    gload16(A  + (long)(m0 + seg * 16 + lrow) * lda + kb + lcol, dA + seg * 512);
    gload16(Bm + (long)(n0 + seg * 16 + lrow) * ldb + kb + lcol, dB + seg * 512);
  };

  const int rslot = 16 * (g ^ ((lo >> 1) & 3));   // read-side slot XOR (bytes)

  floatx4 acc[4][2] = {};

  stage(0); stage(1);
  asm volatile("s_waitcnt vmcnt(2)" ::: "memory");   // tile0 landed
  SBAR();

#pragma unroll 1
  for (int s = 0; s < NTK; ++s) {
    stage(s + 2);                                    // issue-early prefetch
    const bf16_t* bufA = &sA[s % 3][0];
    const bf16_t* bufB = &sB[s % 3][0];
    bf16x8 av[4], bv[2];
#pragma unroll
    for (int i = 0; i < 4; ++i)
      av[i] = *(const bf16x8*)((const char*)(bufA + (wr * 64 + i * 16 + lo) * 32) + rslot);
#pragma unroll
    for (int i = 0; i < 2; ++i)
      bv[i] = *(const bf16x8*)((const char*)(bufB + (wc * 32 + i * 16 + lo) * 32) + rslot);
#pragma unroll
    for (int mi = 0; mi < 4; ++mi)
#pragma unroll
      for (int ni = 0; ni < 2; ++ni)
        acc[mi][ni] = MFMA16(av[mi], bv[ni], acc[mi][ni]);
    if (s + 2 < NTK) { asm volatile("s_waitcnt vmcnt(2)" ::: "memory"); }
    else             { asm volatile("s_waitcnt vmcnt(0)" ::: "memory"); }
    SBAR();
  }

  // ---- epilogue (wave covers rows wr*64+[0,64), cols wc*32+[0,32)) ----
  if constexpr (EPI == EPI_QKV) {
    const int sect = n0 >> 10;        // 0=Q 1=K 2=V
#pragma unroll
    for (int ni = 0; ni < 2; ++ni) {
      const int col = n0 + wc * 32 + ni * 16 + lo;
      const int c10 = col & 1023;
      float bvs = 0.0f;
      if (sect == 0) bvs = bias[c10];
      else if (sect == 2) bvs = bias2[c10];
#pragma unroll
      for (int mi = 0; mi < 4; ++mi) {
#pragma unroll
        for (int r = 0; r < 4; ++r) {
          const int row = m0 + wr * 64 + mi * 16 + g * 4 + r;
          const int s = row & 1023;
          float val = acc[mi][ni][r] + bvs;
          if (sect < 2) {             // rope + scale (table pre-scaled)
            const float2 t = rtab[(s << 6) + ((col & 127) >> 1)];
            const float p = __shfl_xor(val, 1);
            val = val * t.x + p * ((col & 1) ? t.y : -t.y);
            bf16_t* dst = sect ? out2 : (bf16_t*)Cv;
            dst[(long)row * 1024 + c10] = (bf16_t)val;
          } else {                    // vt[b][h*128+d][s]
            out3[((long)(row >> 10) << 20) + ((long)(col - 2048) << 10) + s] = (bf16_t)val;
          }
        }
      }
    }
    return;
  }

#pragma unroll
  for (int ni = 0; ni < 2; ++ni) {
    const int col = n0 + wc * 32 + ni * 16 + lo;
    const float bvs = bias ? bias[col] : 0.0f;
#pragma unroll
    for (int mi = 0; mi < 4; ++mi) {
#pragma unroll
      for (int r = 0; r < 4; ++r) {
        const int row = m0 + wr * 64 + mi * 16 + g * 4 + r;
        float v = acc[mi][ni][r] + bvs;
        if constexpr (EPI == EPI_BF16) {
          ((bf16_t*)Cv)[(long)row * ldc + col] = (bf16_t)v;
        } else if constexpr (EPI == EPI_GELU_BF16) {
          ((bf16_t*)Cv)[(long)row * ldc + col] = (bf16_t)gelu_f(v);
        } else if constexpr (EPI == EPI_GELU_F32) {
          ((float*)Cv)[(long)row * ldc + col] = gelu_f(v);
        } else {  // EPI_RES_F32
          const long idx = (long)row * ldc + col;
          ((float*)Cv)[idx] = res[idx] + v;
        }
      }
    }
  }
}

// ---------------------------------------------------------------------------
// Flash attention (unchanged): grid (S/128, B*H), 4 waves/block.
// ---------------------------------------------------------------------------
__global__ __launch_bounds__(256)
void flash_kernel(const bf16_t* __restrict__ q, const bf16_t* __restrict__ k,
                  const bf16_t* __restrict__ vt, bf16_t* __restrict__ o,
                  const int* __restrict__ xlen)
{
  __shared__ bf16_t sK[2][4096];   // [kv=64][d=128], rows swizzled
  __shared__ bf16_t sV[2][4096];   // [d=128][kv=64], rows swizzled
  __shared__ bf16_t sP[4][2048];   // per-wave [q=32][kv=64], swizzled
  const int tid = threadIdx.x, w = tid >> 6, lane = tid & 63;
  const int lo = lane & 15, g = lane >> 4;
  const int bh = blockIdx.y, b = bh >> 3, h = bh & 7;
  const int q0 = blockIdx.x * 128 + w * 32;
  const int nv  = xlen[b] >> 2;
  const int nkt = (nv + 63) >> 6;
  const long base = (long)b * 1048576 + (long)h * 128;
  const bf16_t* Qp = q + base;
  const bf16_t* Kp = k + base;
  const bf16_t* Vp = vt + (long)b * 1048576 + ((long)h << 17);

  auto stageKV = [&](int kt, int buf) {
    const int kv0 = kt << 6;
#pragma unroll
    for (int j = 0; j < 4; ++j) {
      const int seg = (w << 2) + j;
      {
        const int row = (seg << 2) + (lane >> 4);
        const int col = ((lane & 15) << 3) ^ ((row & 7) << 3);
        gload16(Kp + (long)(kv0 + row) * 1024 + col, &sK[buf][seg * 512]);
      }
      {
        const int row = (seg << 3) + (lane >> 3);
        const int col = ((lane & 7) << 3) ^ ((row & 7) << 3);
        gload16(Vp + (long)row * 1024 + kv0 + col, &sV[buf][seg * 512]);
      }
    }
  };

  bf16x8 qf[2][4];
#pragma unroll
  for (int mi = 0; mi < 2; ++mi)
#pragma unroll
    for (int ks = 0; ks < 4; ++ks)
      qf[mi][ks] = *reinterpret_cast<const bf16x8*>(
          Qp + (long)(q0 + mi * 16 + lo) * 1024 + ks * 32 + g * 8);

  floatx4 of[2][8] = {};
  float m[2][4], l[2][4];
#pragma unroll
  for (int mi = 0; mi < 2; ++mi)
#pragma unroll
    for (int r = 0; r < 4; ++r) { m[mi][r] = -1e30f; l[mi][r] = 0.0f; }

  const char* kbase = (const char*)&sK[0][0];
  const char* vbase = (const char*)&sV[0][0];
  char* pbase = (char*)&sP[w][0];
  const int swzL = (lo & 7) << 4;

  stageKV(0, 0);
  __syncthreads();
  int cur = 0;
#pragma unroll 1
  for (int kt = 0; kt < nkt; ++kt) {
    const int kv0 = kt << 6;
    if (kt + 1 < nkt) stageKV(kt + 1, cur ^ 1);

    floatx4 s[2][4] = {};
#pragma unroll
    for (int ni = 0; ni < 4; ++ni) {
#pragma unroll
      for (int ks = 0; ks < 4; ++ks) {
        const bf16x8 bv = *reinterpret_cast<const bf16x8*>(
            kbase + cur * 8192 + (ni * 16 + lo) * 256 + ((ks * 64 + (g << 4)) ^ swzL));
        s[0][ni] = MFMA16(qf[0][ks], bv, s[0][ni]);
        s[1][ni] = MFMA16(qf[1][ks], bv, s[1][ni]);
      }
    }

#pragma unroll
    for (int mi = 0; mi < 2; ++mi) {
#pragma unroll
      for (int r = 0; r < 4; ++r) {
        float vv[4]; float pm = -1e30f;
#pragma unroll
        for (int ni = 0; ni < 4; ++ni) {
          float val = s[mi][ni][r];
          if (kv0 + ni * 16 + lo >= nv) val = -1e30f;
          vv[ni] = val; pm = fmaxf(pm, val);
        }
        pm = fmaxf(pm, __shfl_xor(pm, 1)); pm = fmaxf(pm, __shfl_xor(pm, 2));
        pm = fmaxf(pm, __shfl_xor(pm, 4)); pm = fmaxf(pm, __shfl_xor(pm, 8));
        const float mo = m[mi][r];
        const float mn = fmaxf(mo, pm);
        const float sc = __expf(mo - mn);
        const int qrow = mi * 16 + g * 4 + r;
        const int sw = (qrow & 7) << 4;
        float ss = 0.0f;
#pragma unroll
        for (int ni = 0; ni < 4; ++ni) {
          const float p = __expf(vv[ni] - mn);
          ss += p;
          *(bf16_t*)(pbase + qrow * 128 + (((ni << 5) + (lo << 1)) ^ sw)) = (bf16_t)p;
        }
        ss += __shfl_xor(ss, 1); ss += __shfl_xor(ss, 2);
        ss += __shfl_xor(ss, 4); ss += __shfl_xor(ss, 8);
        l[mi][r] = l[mi][r] * sc + ss;
        m[mi][r] = mn;
#pragma unroll
        for (int nd = 0; nd < 8; ++nd) of[mi][nd][r] *= sc;
      }
    }

    asm volatile("s_waitcnt lgkmcnt(0)" ::: "memory");
    __builtin_amdgcn_sched_barrier(0);

#pragma unroll
    for (int ks = 0; ks < 2; ++ks) {
      bf16x8 av0 = *reinterpret_cast<const bf16x8*>(
          pbase + (0 * 16 + lo) * 128 + (((ks << 6) + (g << 4)) ^ swzL));
      bf16x8 av1 = *reinterpret_cast<const bf16x8*>(
          pbase + (1 * 16 + lo) * 128 + (((ks << 6) + (g << 4)) ^ swzL));
#pragma unroll
      for (int nd = 0; nd < 8; ++nd) {
        const bf16x8 bv = *reinterpret_cast<const bf16x8*>(
            vbase + cur * 8192 + (nd * 16 + lo) * 128 + (((ks << 6) + (g << 4)) ^ swzL));
        of[0][nd] = MFMA16(av0, bv, of[0][nd]);
        of[1][nd] = MFMA16(av1, bv, of[1][nd]);
      }
    }
    __syncthreads();
    cur ^= 1;
  }

#pragma unroll
  for (int mi = 0; mi < 2; ++mi)
#pragma unroll
    for (int r = 0; r < 4; ++r) {
      const float inv = 1.0f / l[mi][r];
      const long rb = base + (long)(q0 + mi * 16 + g * 4 + r) * 1024;
#pragma unroll
      for (int nd = 0; nd < 8; ++nd)
        o[rb + nd * 16 + lo] = (bf16_t)(of[mi][nd][r] * inv);
    }
}

// LayerNorm: one block per row of 1024 f32 -> bf16
__global__ __launch_bounds__(256)
void ln_kernel(const float* __restrict__ x, bf16_t* __restrict__ y,
               const float* __restrict__ w, const float* __restrict__ b)
{
  const long row = blockIdx.x;
  const float4 v = reinterpret_cast<const float4*>(x + row * ND)[threadIdx.x];
  float s  = v.x + v.y + v.z + v.w;
  float ss = v.x * v.x + v.y * v.y + v.z * v.z + v.w * v.w;
#pragma unroll
  for (int off = 32; off; off >>= 1) { s += __shfl_down(s, off); ss += __shfl_down(ss, off); }
  __shared__ float sh[8];
  if ((threadIdx.x & 63) == 0) { sh[threadIdx.x >> 6] = s; sh[4 + (threadIdx.x >> 6)] = ss; }
  __syncthreads();
  const float tot  = sh[0] + sh[1] + sh[2] + sh[3];
  const float tot2 = sh[4] + sh[5] + sh[6] + sh[7];
  const float mean = tot * (1.0f / ND);
  const float var  = tot2 * (1.0f / ND) - mean * mean;
  const float rstd = rsqrtf(var + 1e-5f);
  const int i0 = threadIdx.x * 4;
  const float vv[4] = {v.x, v.y, v.z, v.w};
  bf16x4 o;
#pragma unroll
  for (int j = 0; j < 4; ++j)
    o[j] = (bf16_t)((vv[j] - mean) * rstd * w[i0 + j] + b[i0 + j]);
  reinterpret_cast<bf16x4*>(y + row * ND)[threadIdx.x] = o;
}

// pre-scaled rope table: rtab[s*64+i] = (cos, sin)(s*f_i) * 128^-0.25
__global__ __launch_bounds__(256)
void rtab_kernel(float2* __restrict__ tab)
{
  const int idx = blockIdx.x * 256 + threadIdx.x;   // 65536
  const int s = idx >> 6, i = idx & 63;
  const float freq = __expf((float)i * -0.14391156831212787f);  // 10000^(-2i/128)
  float sn, cs;
  sincosf((float)s * freq, &sn, &cs);
  const float sc = 0.29730177875068026f;
  tab[idx] = make_float2(cs * sc, sn * sc);
}

// im2col conv1: A1[(b*2048+t), i*3+kk] = x[b, i, 2t+kk-1] (pad 1), f32->bf16
__global__ __launch_bounds__(256)
void im2col1_kernel(const float* __restrict__ x, bf16_t* __restrict__ a)
{
  const long idx = (long)blockIdx.x * 256 + threadIdx.x;
  if (idx >= (long)NB * NT1 * 384) return;
  const int  k = (int)(idx % 384);
  const long m = idx / 384;
  const int i = k / 3, kk = k - 3 * i;
  const int t = (int)(m & (NT1 - 1));
  const int b = (int)(m >> 11);
  const int tt = 2 * t + kk - 1;
  float v = 0.0f;
  if (tt >= 0 && tt < NT) v = x[((long)b * 128 + i) * NT + tt];
  a[idx] = (bf16_t)v;
}

// im2col conv2: A2[(b*1024+t), i*3+kk] = h1[b, 2t+kk-1, i] (pad 1)
__global__ __launch_bounds__(256)
void im2col2_kernel(const bf16_t* __restrict__ h1, bf16_t* __restrict__ a)
{
  const long idx = (long)blockIdx.x * 256 + threadIdx.x;
  if (idx >= (long)NB * NS * 3072) return;
  const int  k = (int)(idx % 3072);
  const long m = idx / 3072;
  const int i = k / 3, kk = k - 3 * i;
  const int t = (int)(m & (NS - 1));
  const int b = (int)(m >> 10);
  const int tt = 2 * t + kk - 1;
  bf16_t v = (bf16_t)0.0f;
  if (tt >= 0 && tt < NT1) v = h1[((long)b * NT1 + tt) * ND + i];
  a[idx] = v;
}

__global__ void ylen_kernel(const int* __restrict__ xlen, float* __restrict__ ylen)
{
  const int b = threadIdx.x;
  if (b < NB) {
    const int y1 = (xlen[b] + 1) >> 1;
    ylen[b] = (float)((y1 + 1) >> 1);
  }
}

__global__ __launch_bounds__(256)
void cvt_kernel(const float* __restrict__ in, bf16_t* __restrict__ out, long n)
{
  const long i = ((long)blockIdx.x * 256 + threadIdx.x) * 4;
  if (i >= n) return;
  const float4 v = *reinterpret_cast<const float4*>(in + i);
  bf16x4 o;
  o[0] = (bf16_t)v.x; o[1] = (bf16_t)v.y; o[2] = (bf16_t)v.z; o[3] = (bf16_t)v.w;
  *reinterpret_cast<bf16x4*>(out + i) = o;
}

// three 1M-element f32 arrays -> one contiguous 3M bf16 region
__global__ __launch_bounds__(256)
void cvt3_kernel(const float* __restrict__ a, const float* __restrict__ b,
                 const float* __restrict__ c, bf16_t* __restrict__ out)
{
  const long i = ((long)blockIdx.x * 256 + threadIdx.x) * 4;
  const float* src; long j;
  if (i < 1048576)      { src = a; j = i; }
  else if (i < 2097152) { src = b; j = i - 1048576; }
  else                  { src = c; j = i - 2097152; }
  const float4 v = *reinterpret_cast<const float4*>(src + j);
  bf16x4 o;
  o[0] = (bf16_t)v.x; o[1] = (bf16_t)v.y; o[2] = (bf16_t)v.z; o[3] = (bf16_t)v.w;
  *reinterpret_cast<bf16x4*>(out + i) = o;
}

// two 4M-element f32 arrays -> one contiguous 8M bf16 region
__global__ __launch_bounds__(256)
void cvt2_kernel(const float* __restrict__ a, const float* __restrict__ b,
                 bf16_t* __restrict__ out)
{
  const long i = ((long)blockIdx.x * 256 + threadIdx.x) * 4;
  const float* src; long j;
  if (i < 4194304) { src = a; j = i; }
  else             { src = b; j = i - 4194304; }
  const float4 v = *reinterpret_cast<const float4*>(src + j);
  bf16x4 o;
  o[0] = (bf16_t)v.x; o[1] = (bf16_t)v.y; o[2] = (bf16_t)v.z; o[3] = (bf16_t)v.w;
  *reinterpret_cast<bf16x4*>(out + i) = o;
}

extern "C" void kernel_launch(void* const* d_in, const int* in_sizes, int n_in,
                              void* d_out, int out_size, void* d_ws, size_t ws_size,
                              hipStream_t stream)
{
  const float* x         = (const float*)d_in[0];
  const int*   x_len     = (const int*)  d_in[1];
  const float* conv1_w   = (const float*)d_in[2];
  const float* conv1_b   = (const float*)d_in[3];
  const float* conv2_w   = (const float*)d_in[4];
  const float* conv2_b   = (const float*)d_in[5];
  const float* attn_ln_w = (const float*)d_in[6];
  const float* attn_ln_b = (const float*)d_in[7];
  const float* q_w   = (const float*)d_in[8];
  const float* q_b   = (const float*)d_in[9];
  const float* k_w   = (const float*)d_in[10];
  const float* v_w   = (const float*)d_in[11];
  const float* v_b   = (const float*)d_in[12];
  const float* out_w = (const float*)d_in[13];
  const float* out_b = (const float*)d_in[14];
  const float* mlp_ln_w = (const float*)d_in[15];
  const float* mlp_ln_b = (const float*)d_in[16];
  const float* mlp1_w = (const float*)d_in[17];
  const float* mlp1_b = (const float*)d_in[18];
  const float* mlp2_w = (const float*)d_in[19];
  const float* mlp2_b = (const float*)d_in[20];
  float* outp = (float*)d_out;
  (void)in_sizes; (void)n_in; (void)out_size;

  const long MB = 1024L * 1024;
  char* ws = (char*)d_ws;
  size_t off = 0;
  auto alloc = [&](size_t bytes) -> char* {
    char* p = ws + off;
    off += (bytes + 255) & ~(size_t)255;
    return p;
  };
  bf16_t* ybuf  = (bf16_t*)alloc(16 * MB);       //  16 MB | a1(conv)
  bf16_t* qbuf  = (bf16_t*)alloc(16 * MB);       //  16 MB | h1[0:16] | Q then O
  char*   R     = alloc(64 * MB);                //  64 MB | h1[16:32]+a2 | kbuf | hid
  char*   wA    = alloc(24 * MB);                //  24 MB | weights/vt/rtab
  const size_t required = off;

  // conv-phase aliases
  bf16_t* a1  = ybuf;                            // 12 MB
  bf16_t* h1  = qbuf;                            // 32 MB (qbuf + R[0:16])
  bf16_t* a2  = (bf16_t*)(R + 16 * MB);          // 48 MB
  bf16_t* c2w = (bf16_t*)wA;                     //  6 MB
  bf16_t* c1w = (bf16_t*)(wA + 8 * MB);          // 0.75 MB
  // persistent
  float2* rtab = (float2*)(wA + 6 * MB);         // 512 KB at [6:6.5], kept
  // layer-phase aliases
  bf16_t* wqkv = (bf16_t*)wA;                    // [0:6]
  bf16_t* vt   = (bf16_t*)(wA + 8 * MB);         // [8:24] during attention
  bf16_t* wo   = (bf16_t*)(wA + 16 * MB);        // [16:18] after flash
  bf16_t* w1b  = (bf16_t*)(wA + 8 * MB);         // [8:16] after attn-out
  bf16_t* w2b  = (bf16_t*)(wA + 16 * MB);        // [16:24]
  bf16_t* kbuf = (bf16_t*)R;                     // [0:16] during attention
  bf16_t* hid  = (bf16_t*)R;                     // 64 MB during MLP

  if (required > ws_size) {
    ylen_kernel<<<dim3(1), 64, 0, stream>>>(x_len, outp + 8L * 1024 * 1024);
    return;
  }

  auto cvt = [&](const float* in, bf16_t* o, long n) {
    cvt_kernel<<<dim3((unsigned)(n / 1024)), 256, 0, stream>>>(in, o, n);
  };

  rtab_kernel<<<dim3(256), 256, 0, stream>>>(rtab);

  // ---- conv stem ----
  cvt(conv1_w, c1w, 1024L * 384);
  cvt(conv2_w, c2w, 1024L * 3072);
  im2col1_kernel<<<dim3((unsigned)((16384L * 384) / 256)), 256, 0, stream>>>(x, a1);
  gemm_bt<EPI_GELU_BF16><<<dim3(128, 8), 512, 0, stream>>>(
      a1, 384, c1w, 384, h1, 1024, conv1_b, nullptr, 384, 1,
      nullptr, nullptr, nullptr, nullptr);
  im2col2_kernel<<<dim3((unsigned)((8192L * 3072) / 256)), 256, 0, stream>>>(h1, a2);
  gemm_bt<EPI_GELU_F32><<<dim3(64, 8), 512, 0, stream>>>(
      a2, 3072, c2w, 3072, outp /*carry*/, 1024, conv2_b, nullptr, 3072, 1,
      nullptr, nullptr, nullptr, nullptr);

  float* carry = outp;  // f32 residual stream lives in d_out

  for (int l = 0; l < 6; ++l) {
    cvt3_kernel<<<dim3(3072), 256, 0, stream>>>(
        q_w + (long)l * 1048576, k_w + (long)l * 1048576, v_w + (long)l * 1048576, wqkv);

    ln_kernel<<<dim3(8192), 256, 0, stream>>>(carry, ybuf, attn_ln_w + l * 1024, attn_ln_b + l * 1024);

    // fused QKV projection + rope/scale + V-transpose (N=3072)
    gemm_bt<EPI_QKV><<<dim3(64, 24), 512, 0, stream>>>(
        ybuf, 1024, wqkv, 1024, qbuf, 1024,
        q_b + l * 1024, nullptr, 1024, 1, kbuf, vt, v_b + l * 1024, rtab);

    // flash attention: O overwrites Q in place
    flash_kernel<<<dim3(8, 64), 256, 0, stream>>>(qbuf, kbuf, vt, qbuf, x_len);

    // carry += O @ ow^T + ob
    cvt(out_w + (long)l * 1048576, wo, 1048576);
    gemm_bt<EPI_RES_F32><<<dim3(64, 8), 512, 0, stream>>>(
        qbuf, 1024, wo, 1024, carry, 1024,
        out_b + l * 1024, carry, 1024, 1, nullptr, nullptr, nullptr, nullptr);

    cvt2_kernel<<<dim3(8192), 256, 0, stream>>>(
        mlp1_w + (long)l * 4194304, mlp2_w + (long)l * 4194304, w1b);

    ln_kernel<<<dim3(8192), 256, 0, stream>>>(carry, ybuf, mlp_ln_w + l * 1024, mlp_ln_b + l * 1024);

    gemm_bt<EPI_GELU_BF16><<<dim3(64, 32), 512, 0, stream>>>(
        ybuf, 1024, w1b, 1024, hid, 4096,
        mlp1_b + (long)l * 4096, nullptr, 1024, 1, nullptr, nullptr, nullptr, nullptr);
    gemm_bt<EPI_RES_F32><<<dim3(64, 8), 512, 0, stream>>>(
        hid, 4096, w2b, 4096, carry, 1024,
        mlp2_b + l * 1024, carry, 4096, 1, nullptr, nullptr, nullptr, nullptr);
  }

  ylen_kernel<<<dim3(1), 64, 0, stream>>>(x_len, outp + 8L * 1024 * 1024);
}

// Round 9
// 2996.148 us; speedup vs baseline: 1.3801x; 1.0046x over previous
//
#include <hip/hip_runtime.h>
#include <hip/hip_bf16.h>
#include <cstdint>
#include <cstddef>

// ---------------------------------------------------------------------------
// AudioEncoder (Whisper-style) forward for MI355X.
// B=8, T=4096, n_mels=128, D=1024, H=8 heads (hd=128), F=4096, L=6, S=1024.
// GEMMs: 128x128 tile, 8 waves (2Mx4N, 512 threads), BK=32, triple-buffered
// LDS with counted vmcnt(2) + raw barrier; read-side XOR swizzle.
// Attention: flash kernel, XCD-locality remap (all q-blocks of one (b,h) on
// one XCD; each XCD serves every batch -> balanced + K/V L2-resident).
// ---------------------------------------------------------------------------

typedef __bf16 bf16_t;
typedef __bf16 bf16x8 __attribute__((ext_vector_type(8)));
typedef __bf16 bf16x4 __attribute__((ext_vector_type(4)));
typedef float  floatx4 __attribute__((ext_vector_type(4)));

#define NB   8
#define NS   1024
#define ND   1024
#define NT   4096
#define NT1  2048

#define MFMA16(a, b, c) __builtin_amdgcn_mfma_f32_16x16x32_bf16(a, b, c, 0, 0, 0)

#define SBAR() do { __builtin_amdgcn_sched_barrier(0); \
                    __builtin_amdgcn_s_barrier();      \
                    __builtin_amdgcn_sched_barrier(0); } while (0)

__device__ __forceinline__ float gelu_f(float x) {
  // tanh-form gelu via sigmoid: 0.5x(1+tanh(z)) = x*sigmoid(2z); |err|<~3e-3
  const float t = 1.5957691216057308f * (x + 0.044715f * x * x * x);
  return x / (1.0f + __expf(-t));
}

__device__ __forceinline__ void gload16(const void* g, void* l) {
  __builtin_amdgcn_global_load_lds(
      (__attribute__((address_space(1))) void*)(const_cast<void*>(g)),
      (__attribute__((address_space(3))) void*)l, 16, 0, 0);
}

enum { EPI_BF16 = 0, EPI_GELU_BF16 = 2, EPI_GELU_F32 = 3, EPI_RES_F32 = 4, EPI_QKV = 5 };

// C = A (M,K) @ B^T, B stored (N,K) row-major. 128x128 tile, 8 waves (2Mx4N),
// each wave 64x32 output as acc[4][2] of 16x16x32-bf16 MFMA frags. 3-buffer
// LDS pipeline: stage(s+2) issued first (1 A + 1 B gload per wave), compute
// buf s, counted vmcnt(2) (tile s+1 landed, s+2 in flight) + raw s_barrier.
// LDS slot-swizzled: inverse-swizzled global source, same XOR on reads.
template<int EPI>
__global__ __launch_bounds__(512)
void gemm_bt(const bf16_t* __restrict__ A, long lda,
             const bf16_t* __restrict__ Bm, long ldb,
             void* Cv, long ldc,
             const float* __restrict__ bias, const float* res,
             int K, int swz,
             bf16_t* out2, bf16_t* out3, const float* __restrict__ bias2,
             const float2* __restrict__ rtab)
{
  __shared__ bf16_t sA[3][4096];   // 3 x 8KB per matrix (48KB total)
  __shared__ bf16_t sB[3][4096];
  const int tid  = threadIdx.x;
  const int wid  = tid >> 6;       // 0..7
  const int lane = tid & 63;
  const int lo = lane & 15, g = lane >> 4;
  const int wr = wid >> 2, wc = wid & 3;   // 2M x 4N wave grid

  int bx = blockIdx.x, by = blockIdx.y;
  if (swz) {               // bijective XCD-chunked remap (grid size % 8 == 0)
    const int gx = gridDim.x;
    const int n  = gx * gridDim.y;
    int id = bx + by * gx;
    id = (id & 7) * (n >> 3) + (id >> 3);
    bx = id % gx; by = id / gx;
  }
  const int m0 = bx * 128, n0 = by * 128;
  const int NTK = K >> 5;

  const int lrow = lane >> 2;                         // LDS row within segment
  const int lcol = 8 * ((lane & 3) ^ ((lane >> 3) & 3));  // inv-swizzled source

  auto stage = [&](int t) {
    if (t >= NTK) return;
    const int kb = t << 5;
    bf16_t* dA = &sA[t % 3][0];
    bf16_t* dB = &sB[t % 3][0];
    const int seg = wid;             // 8 segments x 16 rows x 64B each matrix
    gload16(A  + (long)(m0 + seg * 16 + lrow) * lda + kb + lcol, dA + seg * 512);
    gload16(Bm + (long)(n0 + seg * 16 + lrow) * ldb + kb + lcol, dB + seg * 512);
  };

  const int rslot = 16 * (g ^ ((lo >> 1) & 3));   // read-side slot XOR (bytes)

  floatx4 acc[4][2] = {};

  stage(0); stage(1);
  asm volatile("s_waitcnt vmcnt(2)" ::: "memory");   // tile0 landed
  SBAR();

#pragma unroll 1
  for (int s = 0; s < NTK; ++s) {
    stage(s + 2);                                    // issue-early prefetch
    const bf16_t* bufA = &sA[s % 3][0];
    const bf16_t* bufB = &sB[s % 3][0];
    bf16x8 av[4], bv[2];
#pragma unroll
    for (int i = 0; i < 4; ++i)
      av[i] = *(const bf16x8*)((const char*)(bufA + (wr * 64 + i * 16 + lo) * 32) + rslot);
#pragma unroll
    for (int i = 0; i < 2; ++i)
      bv[i] = *(const bf16x8*)((const char*)(bufB + (wc * 32 + i * 16 + lo) * 32) + rslot);
#pragma unroll
    for (int mi = 0; mi < 4; ++mi)
#pragma unroll
      for (int ni = 0; ni < 2; ++ni)
        acc[mi][ni] = MFMA16(av[mi], bv[ni], acc[mi][ni]);
    if (s + 2 < NTK) { asm volatile("s_waitcnt vmcnt(2)" ::: "memory"); }
    else             { asm volatile("s_waitcnt vmcnt(0)" ::: "memory"); }
    SBAR();
  }

  // ---- epilogue (wave covers rows wr*64+[0,64), cols wc*32+[0,32)) ----
  if constexpr (EPI == EPI_QKV) {
    const int sect = n0 >> 10;        // 0=Q 1=K 2=V
#pragma unroll
    for (int ni = 0; ni < 2; ++ni) {
      const int col = n0 + wc * 32 + ni * 16 + lo;
      const int c10 = col & 1023;
      float bvs = 0.0f;
      if (sect == 0) bvs = bias[c10];
      else if (sect == 2) bvs = bias2[c10];
#pragma unroll
      for (int mi = 0; mi < 4; ++mi) {
#pragma unroll
        for (int r = 0; r < 4; ++r) {
          const int row = m0 + wr * 64 + mi * 16 + g * 4 + r;
          const int s = row & 1023;
          float val = acc[mi][ni][r] + bvs;
          if (sect < 2) {             // rope + scale (table pre-scaled)
            const float2 t = rtab[(s << 6) + ((col & 127) >> 1)];
            const float p = __shfl_xor(val, 1);
            val = val * t.x + p * ((col & 1) ? t.y : -t.y);
            bf16_t* dst = sect ? out2 : (bf16_t*)Cv;
            dst[(long)row * 1024 + c10] = (bf16_t)val;
          } else {                    // vt[b][h*128+d][s]
            out3[((long)(row >> 10) << 20) + ((long)(col - 2048) << 10) + s] = (bf16_t)val;
          }
        }
      }
    }
    return;
  }

#pragma unroll
  for (int ni = 0; ni < 2; ++ni) {
    const int col = n0 + wc * 32 + ni * 16 + lo;
    const float bvs = bias ? bias[col] : 0.0f;
#pragma unroll
    for (int mi = 0; mi < 4; ++mi) {
#pragma unroll
      for (int r = 0; r < 4; ++r) {
        const int row = m0 + wr * 64 + mi * 16 + g * 4 + r;
        float v = acc[mi][ni][r] + bvs;
        if constexpr (EPI == EPI_BF16) {
          ((bf16_t*)Cv)[(long)row * ldc + col] = (bf16_t)v;
        } else if constexpr (EPI == EPI_GELU_BF16) {
          ((bf16_t*)Cv)[(long)row * ldc + col] = (bf16_t)gelu_f(v);
        } else if constexpr (EPI == EPI_GELU_F32) {
          ((float*)Cv)[(long)row * ldc + col] = gelu_f(v);
        } else {  // EPI_RES_F32
          const long idx = (long)row * ldc + col;
          ((float*)Cv)[idx] = res[idx] + v;
        }
      }
    }
  }
}

// ---------------------------------------------------------------------------
// Flash attention: grid (8, 64), 4 waves/block, wave owns 32 q-rows.
// XCD-locality remap: hid = bx + by*8; xcd = hid&7 (round-robin dispatch);
// qx = (hid>>3)&7; bh = xcd + 8*(hid>>6). All 8 q-blocks of a (b,h) pair land
// on one XCD (K/V L2-resident, fetched once); each XCD serves one head of
// every batch (balanced total work per XCD).
// ---------------------------------------------------------------------------
__global__ __launch_bounds__(256)
void flash_kernel(const bf16_t* __restrict__ q, const bf16_t* __restrict__ k,
                  const bf16_t* __restrict__ vt, bf16_t* __restrict__ o,
                  const int* __restrict__ xlen)
{
  __shared__ bf16_t sK[2][4096];   // [kv=64][d=128], rows swizzled
  __shared__ bf16_t sV[2][4096];   // [d=128][kv=64], rows swizzled
  __shared__ bf16_t sP[4][2048];   // per-wave [q=32][kv=64], swizzled
  const int tid = threadIdx.x, w = tid >> 6, lane = tid & 63;
  const int lo = lane & 15, g = lane >> 4;
  const int hid = blockIdx.x + (blockIdx.y << 3);
  const int xcd = hid & 7;
  const int qx  = (hid >> 3) & 7;
  const int bh  = xcd + ((hid >> 6) << 3);
  const int b = bh >> 3, h = bh & 7;
  const int q0 = qx * 128 + w * 32;
  const int nv  = xlen[b] >> 2;
  const int nkt = (nv + 63) >> 6;
  const long base = (long)b * 1048576 + (long)h * 128;
  const bf16_t* Qp = q + base;
  const bf16_t* Kp = k + base;
  const bf16_t* Vp = vt + (long)b * 1048576 + ((long)h << 17);

  auto stageKV = [&](int kt, int buf) {
    const int kv0 = kt << 6;
#pragma unroll
    for (int j = 0; j < 4; ++j) {
      const int seg = (w << 2) + j;
      {
        const int row = (seg << 2) + (lane >> 4);
        const int col = ((lane & 15) << 3) ^ ((row & 7) << 3);
        gload16(Kp + (long)(kv0 + row) * 1024 + col, &sK[buf][seg * 512]);
      }
      {
        const int row = (seg << 3) + (lane >> 3);
        const int col = ((lane & 7) << 3) ^ ((row & 7) << 3);
        gload16(Vp + (long)row * 1024 + kv0 + col, &sV[buf][seg * 512]);
      }
    }
  };

  bf16x8 qf[2][4];
#pragma unroll
  for (int mi = 0; mi < 2; ++mi)
#pragma unroll
    for (int ks = 0; ks < 4; ++ks)
      qf[mi][ks] = *reinterpret_cast<const bf16x8*>(
          Qp + (long)(q0 + mi * 16 + lo) * 1024 + ks * 32 + g * 8);

  floatx4 of[2][8] = {};
  float m[2][4], l[2][4];
#pragma unroll
  for (int mi = 0; mi < 2; ++mi)
#pragma unroll
    for (int r = 0; r < 4; ++r) { m[mi][r] = -1e30f; l[mi][r] = 0.0f; }

  const char* kbase = (const char*)&sK[0][0];
  const char* vbase = (const char*)&sV[0][0];
  char* pbase = (char*)&sP[w][0];
  const int swzL = (lo & 7) << 4;

  stageKV(0, 0);
  __syncthreads();
  int cur = 0;
#pragma unroll 1
  for (int kt = 0; kt < nkt; ++kt) {
    const int kv0 = kt << 6;
    if (kt + 1 < nkt) stageKV(kt + 1, cur ^ 1);

    floatx4 s[2][4] = {};
#pragma unroll
    for (int ni = 0; ni < 4; ++ni) {
#pragma unroll
      for (int ks = 0; ks < 4; ++ks) {
        const bf16x8 bv = *reinterpret_cast<const bf16x8*>(
            kbase + cur * 8192 + (ni * 16 + lo) * 256 + ((ks * 64 + (g << 4)) ^ swzL));
        s[0][ni] = MFMA16(qf[0][ks], bv, s[0][ni]);
        s[1][ni] = MFMA16(qf[1][ks], bv, s[1][ni]);
      }
    }

#pragma unroll
    for (int mi = 0; mi < 2; ++mi) {
#pragma unroll
      for (int r = 0; r < 4; ++r) {
        float vv[4]; float pm = -1e30f;
#pragma unroll
        for (int ni = 0; ni < 4; ++ni) {
          float val = s[mi][ni][r];
          if (kv0 + ni * 16 + lo >= nv) val = -1e30f;
          vv[ni] = val; pm = fmaxf(pm, val);
        }
        pm = fmaxf(pm, __shfl_xor(pm, 1)); pm = fmaxf(pm, __shfl_xor(pm, 2));
        pm = fmaxf(pm, __shfl_xor(pm, 4)); pm = fmaxf(pm, __shfl_xor(pm, 8));
        const float mo = m[mi][r];
        const float mn = fmaxf(mo, pm);
        const float sc = __expf(mo - mn);
        const int qrow = mi * 16 + g * 4 + r;
        const int sw = (qrow & 7) << 4;
        float ss = 0.0f;
#pragma unroll
        for (int ni = 0; ni < 4; ++ni) {
          const float p = __expf(vv[ni] - mn);
          ss += p;
          *(bf16_t*)(pbase + qrow * 128 + (((ni << 5) + (lo << 1)) ^ sw)) = (bf16_t)p;
        }
        ss += __shfl_xor(ss, 1); ss += __shfl_xor(ss, 2);
        ss += __shfl_xor(ss, 4); ss += __shfl_xor(ss, 8);
        l[mi][r] = l[mi][r] * sc + ss;
        m[mi][r] = mn;
#pragma unroll
        for (int nd = 0; nd < 8; ++nd) of[mi][nd][r] *= sc;
      }
    }

    asm volatile("s_waitcnt lgkmcnt(0)" ::: "memory");
    __builtin_amdgcn_sched_barrier(0);

#pragma unroll
    for (int ks = 0; ks < 2; ++ks) {
      bf16x8 av0 = *reinterpret_cast<const bf16x8*>(
          pbase + (0 * 16 + lo) * 128 + (((ks << 6) + (g << 4)) ^ swzL));
      bf16x8 av1 = *reinterpret_cast<const bf16x8*>(
          pbase + (1 * 16 + lo) * 128 + (((ks << 6) + (g << 4)) ^ swzL));
#pragma unroll
      for (int nd = 0; nd < 8; ++nd) {
        const bf16x8 bv = *reinterpret_cast<const bf16x8*>(
            vbase + cur * 8192 + (nd * 16 + lo) * 128 + (((ks << 6) + (g << 4)) ^ swzL));
        of[0][nd] = MFMA16(av0, bv, of[0][nd]);
        of[1][nd] = MFMA16(av1, bv, of[1][nd]);
      }
    }
    __syncthreads();
    cur ^= 1;
  }

#pragma unroll
  for (int mi = 0; mi < 2; ++mi)
#pragma unroll
    for (int r = 0; r < 4; ++r) {
      const float inv = 1.0f / l[mi][r];
      const long rb = base + (long)(q0 + mi * 16 + g * 4 + r) * 1024;
#pragma unroll
      for (int nd = 0; nd < 8; ++nd)
        o[rb + nd * 16 + lo] = (bf16_t)(of[mi][nd][r] * inv);
    }
}

// LayerNorm: one block per row of 1024 f32 -> bf16
__global__ __launch_bounds__(256)
void ln_kernel(const float* __restrict__ x, bf16_t* __restrict__ y,
               const float* __restrict__ w, const float* __restrict__ b)
{
  const long row = blockIdx.x;
  const float4 v = reinterpret_cast<const float4*>(x + row * ND)[threadIdx.x];
  float s  = v.x + v.y + v.z + v.w;
  float ss = v.x * v.x + v.y * v.y + v.z * v.z + v.w * v.w;
#pragma unroll
  for (int off = 32; off; off >>= 1) { s += __shfl_down(s, off); ss += __shfl_down(ss, off); }
  __shared__ float sh[8];
  if ((threadIdx.x & 63) == 0) { sh[threadIdx.x >> 6] = s; sh[4 + (threadIdx.x >> 6)] = ss; }
  __syncthreads();
  const float tot  = sh[0] + sh[1] + sh[2] + sh[3];
  const float tot2 = sh[4] + sh[5] + sh[6] + sh[7];
  const float mean = tot * (1.0f / ND);
  const float var  = tot2 * (1.0f / ND) - mean * mean;
  const float rstd = rsqrtf(var + 1e-5f);
  const int i0 = threadIdx.x * 4;
  const float vv[4] = {v.x, v.y, v.z, v.w};
  bf16x4 o;
#pragma unroll
  for (int j = 0; j < 4; ++j)
    o[j] = (bf16_t)((vv[j] - mean) * rstd * w[i0 + j] + b[i0 + j]);
  reinterpret_cast<bf16x4*>(y + row * ND)[threadIdx.x] = o;
}

// pre-scaled rope table: rtab[s*64+i] = (cos, sin)(s*f_i) * 128^-0.25
__global__ __launch_bounds__(256)
void rtab_kernel(float2* __restrict__ tab)
{
  const int idx = blockIdx.x * 256 + threadIdx.x;   // 65536
  const int s = idx >> 6, i = idx & 63;
  const float freq = __expf((float)i * -0.14391156831212787f);  // 10000^(-2i/128)
  float sn, cs;
  sincosf((float)s * freq, &sn, &cs);
  const float sc = 0.29730177875068026f;
  tab[idx] = make_float2(cs * sc, sn * sc);
}

// im2col conv1: A1[(b*2048+t), i*3+kk] = x[b, i, 2t+kk-1] (pad 1), f32->bf16
__global__ __launch_bounds__(256)
void im2col1_kernel(const float* __restrict__ x, bf16_t* __restrict__ a)
{
  const long idx = (long)blockIdx.x * 256 + threadIdx.x;
  if (idx >= (long)NB * NT1 * 384) return;
  const int  k = (int)(idx % 384);
  const long m = idx / 384;
  const int i = k / 3, kk = k - 3 * i;
  const int t = (int)(m & (NT1 - 1));
  const int b = (int)(m >> 11);
  const int tt = 2 * t + kk - 1;
  float v = 0.0f;
  if (tt >= 0 && tt < NT) v = x[((long)b * 128 + i) * NT + tt];
  a[idx] = (bf16_t)v;
}

// im2col conv2: A2[(b*1024+t), i*3+kk] = h1[b, 2t+kk-1, i] (pad 1)
__global__ __launch_bounds__(256)
void im2col2_kernel(const bf16_t* __restrict__ h1, bf16_t* __restrict__ a)
{
  const long idx = (long)blockIdx.x * 256 + threadIdx.x;
  if (idx >= (long)NB * NS * 3072) return;
  const int  k = (int)(idx % 3072);
  const long m = idx / 3072;
  const int i = k / 3, kk = k - 3 * i;
  const int t = (int)(m & (NS - 1));
  const int b = (int)(m >> 10);
  const int tt = 2 * t + kk - 1;
  bf16_t v = (bf16_t)0.0f;
  if (tt >= 0 && tt < NT1) v = h1[((long)b * NT1 + tt) * ND + i];
  a[idx] = v;
}

__global__ void ylen_kernel(const int* __restrict__ xlen, float* __restrict__ ylen)
{
  const int b = threadIdx.x;
  if (b < NB) {
    const int y1 = (xlen[b] + 1) >> 1;
    ylen[b] = (float)((y1 + 1) >> 1);
  }
}

__global__ __launch_bounds__(256)
void cvt_kernel(const float* __restrict__ in, bf16_t* __restrict__ out, long n)
{
  const long i = ((long)blockIdx.x * 256 + threadIdx.x) * 4;
  if (i >= n) return;
  const float4 v = *reinterpret_cast<const float4*>(in + i);
  bf16x4 o;
  o[0] = (bf16_t)v.x; o[1] = (bf16_t)v.y; o[2] = (bf16_t)v.z; o[3] = (bf16_t)v.w;
  *reinterpret_cast<bf16x4*>(out + i) = o;
}

// three 1M-element f32 arrays -> one contiguous 3M bf16 region
__global__ __launch_bounds__(256)
void cvt3_kernel(const float* __restrict__ a, const float* __restrict__ b,
                 const float* __restrict__ c, bf16_t* __restrict__ out)
{
  const long i = ((long)blockIdx.x * 256 + threadIdx.x) * 4;
  const float* src; long j;
  if (i < 1048576)      { src = a; j = i; }
  else if (i < 2097152) { src = b; j = i - 1048576; }
  else                  { src = c; j = i - 2097152; }
  const float4 v = *reinterpret_cast<const float4*>(src + j);
  bf16x4 o;
  o[0] = (bf16_t)v.x; o[1] = (bf16_t)v.y; o[2] = (bf16_t)v.z; o[3] = (bf16_t)v.w;
  *reinterpret_cast<bf16x4*>(out + i) = o;
}

// two 4M-element f32 arrays -> one contiguous 8M bf16 region
__global__ __launch_bounds__(256)
void cvt2_kernel(const float* __restrict__ a, const float* __restrict__ b,
                 bf16_t* __restrict__ out)
{
  const long i = ((long)blockIdx.x * 256 + threadIdx.x) * 4;
  const float* src; long j;
  if (i < 4194304) { src = a; j = i; }
  else             { src = b; j = i - 4194304; }
  const float4 v = *reinterpret_cast<const float4*>(src + j);
  bf16x4 o;
  o[0] = (bf16_t)v.x; o[1] = (bf16_t)v.y; o[2] = (bf16_t)v.z; o[3] = (bf16_t)v.w;
  *reinterpret_cast<bf16x4*>(out + i) = o;
}

extern "C" void kernel_launch(void* const* d_in, const int* in_sizes, int n_in,
                              void* d_out, int out_size, void* d_ws, size_t ws_size,
                              hipStream_t stream)
{
  const float* x         = (const float*)d_in[0];
  const int*   x_len     = (const int*)  d_in[1];
  const float* conv1_w   = (const float*)d_in[2];
  const float* conv1_b   = (const float*)d_in[3];
  const float* conv2_w   = (const float*)d_in[4];
  const float* conv2_b   = (const float*)d_in[5];
  const float* attn_ln_w = (const float*)d_in[6];
  const float* attn_ln_b = (const float*)d_in[7];
  const float* q_w   = (const float*)d_in[8];
  const float* q_b   = (const float*)d_in[9];
  const float* k_w   = (const float*)d_in[10];
  const float* v_w   = (const float*)d_in[11];
  const float* v_b   = (const float*)d_in[12];
  const float* out_w = (const float*)d_in[13];
  const float* out_b = (const float*)d_in[14];
  const float* mlp_ln_w = (const float*)d_in[15];
  const float* mlp_ln_b = (const float*)d_in[16];
  const float* mlp1_w = (const float*)d_in[17];
  const float* mlp1_b = (const float*)d_in[18];
  const float* mlp2_w = (const float*)d_in[19];
  const float* mlp2_b = (const float*)d_in[20];
  float* outp = (float*)d_out;
  (void)in_sizes; (void)n_in; (void)out_size;

  const long MB = 1024L * 1024;
  char* ws = (char*)d_ws;
  size_t off = 0;
  auto alloc = [&](size_t bytes) -> char* {
    char* p = ws + off;
    off += (bytes + 255) & ~(size_t)255;
    return p;
  };
  bf16_t* ybuf  = (bf16_t*)alloc(16 * MB);       //  16 MB | a1(conv)
  bf16_t* qbuf  = (bf16_t*)alloc(16 * MB);       //  16 MB | h1[0:16] | Q then O
  char*   R     = alloc(64 * MB);                //  64 MB | h1[16:32]+a2 | kbuf | hid
  char*   wA    = alloc(24 * MB);                //  24 MB | weights/vt/rtab
  const size_t required = off;

  // conv-phase aliases
  bf16_t* a1  = ybuf;                            // 12 MB
  bf16_t* h1  = qbuf;                            // 32 MB (qbuf + R[0:16])
  bf16_t* a2  = (bf16_t*)(R + 16 * MB);          // 48 MB
  bf16_t* c2w = (bf16_t*)wA;                     //  6 MB
  bf16_t* c1w = (bf16_t*)(wA + 8 * MB);          // 0.75 MB
  // persistent
  float2* rtab = (float2*)(wA + 6 * MB);         // 512 KB at [6:6.5], kept
  // layer-phase aliases
  bf16_t* wqkv = (bf16_t*)wA;                    // [0:6]
  bf16_t* vt   = (bf16_t*)(wA + 8 * MB);         // [8:24] during attention
  bf16_t* wo   = (bf16_t*)(wA + 16 * MB);        // [16:18] after flash
  bf16_t* w1b  = (bf16_t*)(wA + 8 * MB);         // [8:16] after attn-out
  bf16_t* w2b  = (bf16_t*)(wA + 16 * MB);        // [16:24]
  bf16_t* kbuf = (bf16_t*)R;                     // [0:16] during attention
  bf16_t* hid  = (bf16_t*)R;                     // 64 MB during MLP

  if (required > ws_size) {
    ylen_kernel<<<dim3(1), 64, 0, stream>>>(x_len, outp + 8L * 1024 * 1024);
    return;
  }

  auto cvt = [&](const float* in, bf16_t* o, long n) {
    cvt_kernel<<<dim3((unsigned)(n / 1024)), 256, 0, stream>>>(in, o, n);
  };

  rtab_kernel<<<dim3(256), 256, 0, stream>>>(rtab);

  // ---- conv stem ----
  cvt(conv1_w, c1w, 1024L * 384);
  cvt(conv2_w, c2w, 1024L * 3072);
  im2col1_kernel<<<dim3((unsigned)((16384L * 384) / 256)), 256, 0, stream>>>(x, a1);
  gemm_bt<EPI_GELU_BF16><<<dim3(128, 8), 512, 0, stream>>>(
      a1, 384, c1w, 384, h1, 1024, conv1_b, nullptr, 384, 1,
      nullptr, nullptr, nullptr, nullptr);
  im2col2_kernel<<<dim3((unsigned)((8192L * 3072) / 256)), 256, 0, stream>>>(h1, a2);
  gemm_bt<EPI_GELU_F32><<<dim3(64, 8), 512, 0, stream>>>(
      a2, 3072, c2w, 3072, outp /*carry*/, 1024, conv2_b, nullptr, 3072, 1,
      nullptr, nullptr, nullptr, nullptr);

  float* carry = outp;  // f32 residual stream lives in d_out

  for (int l = 0; l < 6; ++l) {
    cvt3_kernel<<<dim3(3072), 256, 0, stream>>>(
        q_w + (long)l * 1048576, k_w + (long)l * 1048576, v_w + (long)l * 1048576, wqkv);

    ln_kernel<<<dim3(8192), 256, 0, stream>>>(carry, ybuf, attn_ln_w + l * 1024, attn_ln_b + l * 1024);

    // fused QKV projection + rope/scale + V-transpose (N=3072)
    gemm_bt<EPI_QKV><<<dim3(64, 24), 512, 0, stream>>>(
        ybuf, 1024, wqkv, 1024, qbuf, 1024,
        q_b + l * 1024, nullptr, 1024, 1, kbuf, vt, v_b + l * 1024, rtab);

    // flash attention: O overwrites Q in place
    flash_kernel<<<dim3(8, 64), 256, 0, stream>>>(qbuf, kbuf, vt, qbuf, x_len);

    // carry += O @ ow^T + ob
    cvt(out_w + (long)l * 1048576, wo, 1048576);
    gemm_bt<EPI_RES_F32><<<dim3(64, 8), 512, 0, stream>>>(
        qbuf, 1024, wo, 1024, carry, 1024,
        out_b + l * 1024, carry, 1024, 1, nullptr, nullptr, nullptr, nullptr);

    cvt2_kernel<<<dim3(8192), 256, 0, stream>>>(
        mlp1_w + (long)l * 4194304, mlp2_w + (long)l * 4194304, w1b);

    ln_kernel<<<dim3(8192), 256, 0, stream>>>(carry, ybuf, mlp_ln_w + l * 1024, mlp_ln_b + l * 1024);

    gemm_bt<EPI_GELU_BF16><<<dim3(64, 32), 512, 0, stream>>>(
        ybuf, 1024, w1b, 1024, hid, 4096,
        mlp1_b + (long)l * 4096, nullptr, 1024, 1, nullptr, nullptr, nullptr, nullptr);
    gemm_bt<EPI_RES_F32><<<dim3(64, 8), 512, 0, stream>>>(
        hid, 4096, w2b, 4096, carry, 1024,
        mlp2_b + l * 1024, carry, 4096, 1, nullptr, nullptr, nullptr, nullptr);
  }

  ylen_kernel<<<dim3(1), 64, 0, stream>>>(x_len, outp + 8L * 1024 * 1024);
}

// Round 11
// 2958.693 us; speedup vs baseline: 1.3976x; 1.0127x over previous
//
#include <hip/hip_runtime.h>
#include <hip/hip_bf16.h>
#include <cstdint>
#include <cstddef>

// ---------------------------------------------------------------------------
// AudioEncoder (Whisper-style) forward for MI355X.
// B=8, T=4096, n_mels=128, D=1024, H=8 heads (hd=128), F=4096, L=6, S=1024.
// GEMMs: 128x128 tile, 8 waves (2Mx4N, 512 threads), BK=32, triple-buffered
// LDS with counted vmcnt(2) + raw barrier; read-side XOR swizzle.
// Attention: flash, KVBLK=32 with TRUE disjoint double buffers (r10 bug:
// tile size was 2x buffer stride -> prefetch raced with compute since r5),
// QBLK=64, 16 waves/CU, XCD-locality remap, defer-max, setprio.
// ---------------------------------------------------------------------------

typedef __bf16 bf16_t;
typedef __bf16 bf16x8 __attribute__((ext_vector_type(8)));
typedef __bf16 bf16x4 __attribute__((ext_vector_type(4)));
typedef float  floatx4 __attribute__((ext_vector_type(4)));

#define NB   8
#define NS   1024
#define ND   1024
#define NT   4096
#define NT1  2048

#define MFMA16(a, b, c) __builtin_amdgcn_mfma_f32_16x16x32_bf16(a, b, c, 0, 0, 0)

#define SBAR() do { __builtin_amdgcn_sched_barrier(0); \
                    __builtin_amdgcn_s_barrier();      \
                    __builtin_amdgcn_sched_barrier(0); } while (0)

__device__ __forceinline__ float gelu_f(float x) {
  // tanh-form gelu via sigmoid: 0.5x(1+tanh(z)) = x*sigmoid(2z); |err|<~3e-3
  const float t = 1.5957691216057308f * (x + 0.044715f * x * x * x);
  return x / (1.0f + __expf(-t));
}

__device__ __forceinline__ void gload16(const void* g, void* l) {
  __builtin_amdgcn_global_load_lds(
      (__attribute__((address_space(1))) void*)(const_cast<void*>(g)),
      (__attribute__((address_space(3))) void*)l, 16, 0, 0);
}

enum { EPI_BF16 = 0, EPI_GELU_BF16 = 2, EPI_GELU_F32 = 3, EPI_RES_F32 = 4, EPI_QKV = 5 };

// C = A (M,K) @ B^T, B stored (N,K) row-major. 128x128 tile, 8 waves (2Mx4N),
// each wave 64x32 output as acc[4][2]. 3-buffer LDS pipeline, counted
// vmcnt(2) + raw s_barrier, read-side XOR swizzle (unchanged from round 8).
template<int EPI>
__global__ __launch_bounds__(512)
void gemm_bt(const bf16_t* __restrict__ A, long lda,
             const bf16_t* __restrict__ Bm, long ldb,
             void* Cv, long ldc,
             const float* __restrict__ bias, const float* res,
             int K, int swz,
             bf16_t* out2, bf16_t* out3, const float* __restrict__ bias2,
             const float2* __restrict__ rtab)
{
  __shared__ bf16_t sA[3][4096];   // 3 x 8KB per matrix (48KB total)
  __shared__ bf16_t sB[3][4096];
  const int tid  = threadIdx.x;
  const int wid  = tid >> 6;       // 0..7
  const int lane = tid & 63;
  const int lo = lane & 15, g = lane >> 4;
  const int wr = wid >> 2, wc = wid & 3;   // 2M x 4N wave grid

  int bx = blockIdx.x, by = blockIdx.y;
  if (swz) {               // bijective XCD-chunked remap (grid size % 8 == 0)
    const int gx = gridDim.x;
    const int n  = gx * gridDim.y;
    int id = bx + by * gx;
    id = (id & 7) * (n >> 3) + (id >> 3);
    bx = id % gx; by = id / gx;
  }
  const int m0 = bx * 128, n0 = by * 128;
  const int NTK = K >> 5;

  const int lrow = lane >> 2;                         // LDS row within segment
  const int lcol = 8 * ((lane & 3) ^ ((lane >> 3) & 3));  // inv-swizzled source

  auto stage = [&](int t) {
    if (t >= NTK) return;
    const int kb = t << 5;
    bf16_t* dA = &sA[t % 3][0];
    bf16_t* dB = &sB[t % 3][0];
    const int seg = wid;             // 8 segments x 16 rows x 64B each matrix
    gload16(A  + (long)(m0 + seg * 16 + lrow) * lda + kb + lcol, dA + seg * 512);
    gload16(Bm + (long)(n0 + seg * 16 + lrow) * ldb + kb + lcol, dB + seg * 512);
  };

  const int rslot = 16 * (g ^ ((lo >> 1) & 3));   // read-side slot XOR (bytes)

  floatx4 acc[4][2] = {};

  stage(0); stage(1);
  asm volatile("s_waitcnt vmcnt(2)" ::: "memory");   // tile0 landed
  SBAR();

#pragma unroll 1
  for (int s = 0; s < NTK; ++s) {
    stage(s + 2);                                    // issue-early prefetch
    const bf16_t* bufA = &sA[s % 3][0];
    const bf16_t* bufB = &sB[s % 3][0];
    bf16x8 av[4], bv[2];
#pragma unroll
    for (int i = 0; i < 4; ++i)
      av[i] = *(const bf16x8*)((const char*)(bufA + (wr * 64 + i * 16 + lo) * 32) + rslot);
#pragma unroll
    for (int i = 0; i < 2; ++i)
      bv[i] = *(const bf16x8*)((const char*)(bufB + (wc * 32 + i * 16 + lo) * 32) + rslot);
#pragma unroll
    for (int mi = 0; mi < 4; ++mi)
#pragma unroll
      for (int ni = 0; ni < 2; ++ni)
        acc[mi][ni] = MFMA16(av[mi], bv[ni], acc[mi][ni]);
    if (s + 2 < NTK) { asm volatile("s_waitcnt vmcnt(2)" ::: "memory"); }
    else             { asm volatile("s_waitcnt vmcnt(0)" ::: "memory"); }
    SBAR();
  }

  // ---- epilogue (wave covers rows wr*64+[0,64), cols wc*32+[0,32)) ----
  if constexpr (EPI == EPI_QKV) {
    const int sect = n0 >> 10;        // 0=Q 1=K 2=V
#pragma unroll
    for (int ni = 0; ni < 2; ++ni) {
      const int col = n0 + wc * 32 + ni * 16 + lo;
      const int c10 = col & 1023;
      float bvs = 0.0f;
      if (sect == 0) bvs = bias[c10];
      else if (sect == 2) bvs = bias2[c10];
#pragma unroll
      for (int mi = 0; mi < 4; ++mi) {
#pragma unroll
        for (int r = 0; r < 4; ++r) {
          const int row = m0 + wr * 64 + mi * 16 + g * 4 + r;
          const int s = row & 1023;
          float val = acc[mi][ni][r] + bvs;
          if (sect < 2) {             // rope + scale (table pre-scaled)
            const float2 t = rtab[(s << 6) + ((col & 127) >> 1)];
            const float p = __shfl_xor(val, 1);
            val = val * t.x + p * ((col & 1) ? t.y : -t.y);
            bf16_t* dst = sect ? out2 : (bf16_t*)Cv;
            dst[(long)row * 1024 + c10] = (bf16_t)val;
          } else {                    // vt[b][h*128+d][s]
            out3[((long)(row >> 10) << 20) + ((long)(col - 2048) << 10) + s] = (bf16_t)val;
          }
        }
      }
    }
    return;
  }

#pragma unroll
  for (int ni = 0; ni < 2; ++ni) {
    const int col = n0 + wc * 32 + ni * 16 + lo;
    const float bvs = bias ? bias[col] : 0.0f;
#pragma unroll
    for (int mi = 0; mi < 4; ++mi) {
#pragma unroll
      for (int r = 0; r < 4; ++r) {
        const int row = m0 + wr * 64 + mi * 16 + g * 4 + r;
        float v = acc[mi][ni][r] + bvs;
        if constexpr (EPI == EPI_BF16) {
          ((bf16_t*)Cv)[(long)row * ldc + col] = (bf16_t)v;
        } else if constexpr (EPI == EPI_GELU_BF16) {
          ((bf16_t*)Cv)[(long)row * ldc + col] = (bf16_t)gelu_f(v);
        } else if constexpr (EPI == EPI_GELU_F32) {
          ((float*)Cv)[(long)row * ldc + col] = gelu_f(v);
        } else {  // EPI_RES_F32
          const long idx = (long)row * ldc + col;
          ((float*)Cv)[idx] = res[idx] + v;
        }
      }
    }
  }
}

// ---------------------------------------------------------------------------
// Flash attention: grid (16, 64), 4 waves/block, wave owns 16 q-rows.
// KVBLK=32: K tile [32][128] = 4096 elems = EXACTLY one sK buffer; V tile
// [128][32] = one sV buffer; double buffers truly disjoint (prefetch of tile
// kt+1 into cur^1 cannot touch cur or sP). LDS 36KB -> 4 blocks/CU = 16
// waves/CU with __launch_bounds__(256,4).
// Swizzles (rule 21: linear gload_lds dest + inverse-swizzled global source,
// same XOR on reads): K rows 256B -> XOR (row&7)<<4; V/P rows 64B -> XOR
// (row&3)<<4.
// XCD remap: hid = bx + by*16; h = hid&7 (XCD via round-robin dispatch);
// qx = (hid>>3)&15; b = hid>>7. Bijective; each XCD serves one head of every
// batch (balanced work, K/V L2-resident).
// ---------------------------------------------------------------------------
__global__ __launch_bounds__(256, 4)
void flash_kernel(const bf16_t* __restrict__ q, const bf16_t* __restrict__ k,
                  const bf16_t* __restrict__ vt, bf16_t* __restrict__ o,
                  const int* __restrict__ xlen)
{
  __shared__ bf16_t sK[2][4096];   // [buf][kv=32][d=128]
  __shared__ bf16_t sV[2][4096];   // [buf][d=128][kv=32]
  __shared__ bf16_t sP[4][512];    // per-wave [q=16][kv=32]
  const int tid = threadIdx.x, w = tid >> 6, lane = tid & 63;
  const int lo = lane & 15, g = lane >> 4;
  const int hid = blockIdx.x + (blockIdx.y << 4);
  const int h   = hid & 7;
  const int qx  = (hid >> 3) & 15;
  const int b   = hid >> 7;
  const int q0 = qx * 64 + w * 16;
  const int nv  = xlen[b] >> 2;            // valid kv columns (>= 512)
  const int nkt = (nv + 31) >> 5;          // tiles of 32
  const long base = (long)b * 1048576 + (long)h * 128;
  const bf16_t* Qp = q + base;
  const bf16_t* Kp = k + base;
  const bf16_t* Vp = vt + (long)b * 1048576 + ((long)h << 17);  // [d][s]

  // stage one K/V tile (inverse-swizzled source, linear LDS dest)
  auto stageKV = [&](int kt, int buf) {
    const int kv0 = kt << 5;
#pragma unroll
    for (int jj = 0; jj < 2; ++jj) {
      const int seg = (w << 1) + jj;                 // 0..7, wave-uniform
      {
        const int row = (seg << 2) + (lane >> 4);    // kv row 0..31
        const int col = ((lane & 15) << 3) ^ ((row & 7) << 3);   // elems
        gload16(Kp + (long)(kv0 + row) * 1024 + col, &sK[buf][seg * 512]);
      }
      {
        const int row = (seg << 4) + (lane >> 2);    // d row 0..127
        const int col = ((lane & 3) << 3) ^ ((row & 3) << 3);    // elems < 32
        gload16(Vp + (long)row * 1024 + kv0 + col, &sV[buf][seg * 512]);
      }
    }
  };

  // Q fragments, held for the whole kernel
  bf16x8 qf[4];
#pragma unroll
  for (int ks = 0; ks < 4; ++ks)
    qf[ks] = *reinterpret_cast<const bf16x8*>(
        Qp + (long)(q0 + lo) * 1024 + ks * 32 + g * 8);

  floatx4 of[8] = {};
  float m[4], l[4];
#pragma unroll
  for (int r = 0; r < 4; ++r) { m[r] = -1e30f; l[r] = 0.0f; }

  const char* kbase = (const char*)&sK[0][0];
  const char* vbase = (const char*)&sV[0][0];
  char* pbase = (char*)&sP[w][0];
  const int swzK = (lo & 7) << 4;   // K rows: 256B, XOR bits 4-6
  const int swzV = (lo & 3) << 4;   // V/P rows: 64B, XOR bits 4-5

  stageKV(0, 0);
  __syncthreads();
  int cur = 0;
#pragma unroll 1
  for (int kt = 0; kt < nkt; ++kt) {
    const int kv0 = kt << 5;
    if (kt + 1 < nkt) stageKV(kt + 1, cur ^ 1);

    // S = Q @ K^T over 32 kv cols (8 MFMA)
    floatx4 s[2] = {};
    __builtin_amdgcn_s_setprio(1);
#pragma unroll
    for (int ni = 0; ni < 2; ++ni) {
#pragma unroll
      for (int ks = 0; ks < 4; ++ks) {
        const bf16x8 bv = *reinterpret_cast<const bf16x8*>(
            kbase + cur * 8192 + (ni * 16 + lo) * 256 + ((ks * 64 + (g << 4)) ^ swzK));
        s[ni] = MFMA16(qf[ks], bv, s[ni]);
      }
    }
    __builtin_amdgcn_s_setprio(0);

    // per-row masked max, then wave-uniform defer-max vote
    float pmv[4];
#pragma unroll
    for (int r = 0; r < 4; ++r) {
      float pm = -1e30f;
#pragma unroll
      for (int ni = 0; ni < 2; ++ni) {
        float val = s[ni][r];
        if (kv0 + ni * 16 + lo >= nv) val = -1e30f;
        pm = fmaxf(pm, val);
      }
      pm = fmaxf(pm, __shfl_xor(pm, 1)); pm = fmaxf(pm, __shfl_xor(pm, 2));
      pm = fmaxf(pm, __shfl_xor(pm, 4)); pm = fmaxf(pm, __shfl_xor(pm, 8));
      pmv[r] = pm;
    }
    const bool skip = __all((pmv[0] <= m[0] + 8.0f) & (pmv[1] <= m[1] + 8.0f) &
                            (pmv[2] <= m[2] + 8.0f) & (pmv[3] <= m[3] + 8.0f));

#pragma unroll
    for (int r = 0; r < 4; ++r) {
      float mn = m[r];
      if (!skip) {
        mn = fmaxf(m[r], pmv[r]);
        const float sc = __expf(m[r] - mn);
        l[r] *= sc;
#pragma unroll
        for (int nd = 0; nd < 8; ++nd) of[nd][r] *= sc;
        m[r] = mn;
      }
      const int qrow = g * 4 + r;
      const int sw = (qrow & 3) << 4;
      float ss = 0.0f;
#pragma unroll
      for (int ni = 0; ni < 2; ++ni) {
        float val = s[ni][r];
        if (kv0 + ni * 16 + lo >= nv) val = -1e30f;
        const float p = __expf(val - mn);
        ss += p;
        *(bf16_t*)(pbase + qrow * 64 + (((ni << 5) + (lo << 1)) ^ sw)) = (bf16_t)p;
      }
      ss += __shfl_xor(ss, 1); ss += __shfl_xor(ss, 2);
      ss += __shfl_xor(ss, 4); ss += __shfl_xor(ss, 8);
      l[r] += ss;
    }

    // RAW: P writes visible before A-frag reads (rule 18: + sched_barrier)
    asm volatile("s_waitcnt lgkmcnt(0)" ::: "memory");
    __builtin_amdgcn_sched_barrier(0);

    // O += P @ V (8 MFMA, single K=32 step)
    __builtin_amdgcn_s_setprio(1);
    {
      const bf16x8 av = *reinterpret_cast<const bf16x8*>(
          pbase + lo * 64 + ((g << 4) ^ swzV));
#pragma unroll
      for (int nd = 0; nd < 8; ++nd) {
        const bf16x8 bv = *reinterpret_cast<const bf16x8*>(
            vbase + cur * 8192 + (nd * 16 + lo) * 64 + ((g << 4) ^ swzV));
        of[nd] = MFMA16(av, bv, of[nd]);
      }
    }
    __builtin_amdgcn_s_setprio(0);
    __syncthreads();   // drains gload (next tile landed) + all LDS reads done
    cur ^= 1;
  }

  // epilogue: normalize and write O (in place over Q region)
#pragma unroll
  for (int r = 0; r < 4; ++r) {
    const float inv = 1.0f / l[r];
    const long rb = base + (long)(q0 + g * 4 + r) * 1024;
#pragma unroll
    for (int nd = 0; nd < 8; ++nd)
      o[rb + nd * 16 + lo] = (bf16_t)(of[nd][r] * inv);
  }
}

// LayerNorm: one block per row of 1024 f32 -> bf16
__global__ __launch_bounds__(256)
void ln_kernel(const float* __restrict__ x, bf16_t* __restrict__ y,
               const float* __restrict__ w, const float* __restrict__ b)
{
  const long row = blockIdx.x;
  const float4 v = reinterpret_cast<const float4*>(x + row * ND)[threadIdx.x];
  float s  = v.x + v.y + v.z + v.w;
  float ss = v.x * v.x + v.y * v.y + v.z * v.z + v.w * v.w;
#pragma unroll
  for (int off = 32; off; off >>= 1) { s += __shfl_down(s, off); ss += __shfl_down(ss, off); }
  __shared__ float sh[8];
  if ((threadIdx.x & 63) == 0) { sh[threadIdx.x >> 6] = s; sh[4 + (threadIdx.x >> 6)] = ss; }
  __syncthreads();
  const float tot  = sh[0] + sh[1] + sh[2] + sh[3];
  const float tot2 = sh[4] + sh[5] + sh[6] + sh[7];
  const float mean = tot * (1.0f / ND);
  const float var  = tot2 * (1.0f / ND) - mean * mean;
  const float rstd = rsqrtf(var + 1e-5f);
  const int i0 = threadIdx.x * 4;
  const float vv[4] = {v.x, v.y, v.z, v.w};
  bf16x4 o;
#pragma unroll
  for (int j = 0; j < 4; ++j)
    o[j] = (bf16_t)((vv[j] - mean) * rstd * w[i0 + j] + b[i0 + j]);
  reinterpret_cast<bf16x4*>(y + row * ND)[threadIdx.x] = o;
}

// pre-scaled rope table: rtab[s*64+i] = (cos, sin)(s*f_i) * 128^-0.25
__global__ __launch_bounds__(256)
void rtab_kernel(float2* __restrict__ tab)
{
  const int idx = blockIdx.x * 256 + threadIdx.x;   // 65536
  const int s = idx >> 6, i = idx & 63;
  const float freq = __expf((float)i * -0.14391156831212787f);  // 10000^(-2i/128)
  float sn, cs;
  sincosf((float)s * freq, &sn, &cs);
  const float sc = 0.29730177875068026f;
  tab[idx] = make_float2(cs * sc, sn * sc);
}

// im2col conv1: A1[(b*2048+t), i*3+kk] = x[b, i, 2t+kk-1] (pad 1), f32->bf16
__global__ __launch_bounds__(256)
void im2col1_kernel(const float* __restrict__ x, bf16_t* __restrict__ a)
{
  const long idx = (long)blockIdx.x * 256 + threadIdx.x;
  if (idx >= (long)NB * NT1 * 384) return;
  const int  k = (int)(idx % 384);
  const long m = idx / 384;
  const int i = k / 3, kk = k - 3 * i;
  const int t = (int)(m & (NT1 - 1));
  const int b = (int)(m >> 11);
  const int tt = 2 * t + kk - 1;
  float v = 0.0f;
  if (tt >= 0 && tt < NT) v = x[((long)b * 128 + i) * NT + tt];
  a[idx] = (bf16_t)v;
}

// im2col conv2: A2[(b*1024+t), i*3+kk] = h1[b, 2t+kk-1, i] (pad 1)
__global__ __launch_bounds__(256)
void im2col2_kernel(const bf16_t* __restrict__ h1, bf16_t* __restrict__ a)
{
  const long idx = (long)blockIdx.x * 256 + threadIdx.x;
  if (idx >= (long)NB * NS * 3072) return;
  const int  k = (int)(idx % 3072);
  const long m = idx / 3072;
  const int i = k / 3, kk = k - 3 * i;
  const int t = (int)(m & (NS - 1));
  const int b = (int)(m >> 10);
  const int tt = 2 * t + kk - 1;
  bf16_t v = (bf16_t)0.0f;
  if (tt >= 0 && tt < NT1) v = h1[((long)b * NT1 + tt) * ND + i];
  a[idx] = v;
}

__global__ void ylen_kernel(const int* __restrict__ xlen, float* __restrict__ ylen)
{
  const int b = threadIdx.x;
  if (b < NB) {
    const int y1 = (xlen[b] + 1) >> 1;
    ylen[b] = (float)((y1 + 1) >> 1);
  }
}

__global__ __launch_bounds__(256)
void cvt_kernel(const float* __restrict__ in, bf16_t* __restrict__ out, long n)
{
  const long i = ((long)blockIdx.x * 256 + threadIdx.x) * 4;
  if (i >= n) return;
  const float4 v = *reinterpret_cast<const float4*>(in + i);
  bf16x4 o;
  o[0] = (bf16_t)v.x; o[1] = (bf16_t)v.y; o[2] = (bf16_t)v.z; o[3] = (bf16_t)v.w;
  *reinterpret_cast<bf16x4*>(out + i) = o;
}

// per-layer weight conversion in ONE launch: q,k,v -> wqkv (3M elems),
// ow -> wo (1M), w1 -> w1b (4M), w2 -> w2b (4M). 12M elems total.
__global__ __launch_bounds__(256)
void cvt_layer_kernel(const float* __restrict__ qw, const float* __restrict__ kw,
                      const float* __restrict__ vw, const float* __restrict__ ow,
                      const float* __restrict__ w1, const float* __restrict__ w2,
                      bf16_t* __restrict__ wqkv, bf16_t* __restrict__ wo,
                      bf16_t* __restrict__ w1b, bf16_t* __restrict__ w2b)
{
  const long i = ((long)blockIdx.x * 256 + threadIdx.x) * 4;
  const float* src; bf16_t* dst;
  if (i < 3145728) {
    dst = wqkv + i;
    if (i < 1048576)      { src = qw + i; }
    else if (i < 2097152) { src = kw + (i - 1048576); }
    else                  { src = vw + (i - 2097152); }
  } else if (i < 4194304) { src = ow + (i - 3145728); dst = wo  + (i - 3145728); }
  else if (i < 8388608)   { src = w1 + (i - 4194304); dst = w1b + (i - 4194304); }
  else                    { src = w2 + (i - 8388608); dst = w2b + (i - 8388608); }
  const float4 v = *reinterpret_cast<const float4*>(src);
  bf16x4 o;
  o[0] = (bf16_t)v.x; o[1] = (bf16_t)v.y; o[2] = (bf16_t)v.z; o[3] = (bf16_t)v.w;
  *reinterpret_cast<bf16x4*>(dst) = o;
}

extern "C" void kernel_launch(void* const* d_in, const int* in_sizes, int n_in,
                              void* d_out, int out_size, void* d_ws, size_t ws_size,
                              hipStream_t stream)
{
  const float* x         = (const float*)d_in[0];
  const int*   x_len     = (const int*)  d_in[1];
  const float* conv1_w   = (const float*)d_in[2];
  const float* conv1_b   = (const float*)d_in[3];
  const float* conv2_w   = (const float*)d_in[4];
  const float* conv2_b   = (const float*)d_in[5];
  const float* attn_ln_w = (const float*)d_in[6];
  const float* attn_ln_b = (const float*)d_in[7];
  const float* q_w   = (const float*)d_in[8];
  const float* q_b   = (const float*)d_in[9];
  const float* k_w   = (const float*)d_in[10];
  const float* v_w   = (const float*)d_in[11];
  const float* v_b   = (const float*)d_in[12];
  const float* out_w = (const float*)d_in[13];
  const float* out_b = (const float*)d_in[14];
  const float* mlp_ln_w = (const float*)d_in[15];
  const float* mlp_ln_b = (const float*)d_in[16];
  const float* mlp1_w = (const float*)d_in[17];
  const float* mlp1_b = (const float*)d_in[18];
  const float* mlp2_w = (const float*)d_in[19];
  const float* mlp2_b = (const float*)d_in[20];
  float* outp = (float*)d_out;
  (void)in_sizes; (void)n_in; (void)out_size;

  const long MB = 1024L * 1024;
  char* ws = (char*)d_ws;
  size_t off = 0;
  auto alloc = [&](size_t bytes) -> char* {
    char* p = ws + off;
    off += (bytes + 255) & ~(size_t)255;
    return p;
  };
  bf16_t* ybuf  = (bf16_t*)alloc(16 * MB);       //  16 MB | a1(conv)
  bf16_t* qbuf  = (bf16_t*)alloc(16 * MB);       //  16 MB | h1[0:16] | Q then O
  char*   R     = alloc(64 * MB);                //  64 MB | h1[16:32]+a2 | kbuf+vt | hid
  char*   wA    = alloc(25 * MB);                //  25 MB | weights/rtab
  const size_t required = off;                   // ~121 MB

  // conv-phase aliases
  bf16_t* a1  = ybuf;                            // 12 MB
  bf16_t* h1  = qbuf;                            // 32 MB (qbuf + R[0:16])
  bf16_t* a2  = (bf16_t*)(R + 16 * MB);          // 48 MB
  bf16_t* c2w = (bf16_t*)wA;                     //  6 MB
  bf16_t* c1w = (bf16_t*)(wA + 8 * MB);          // 0.75 MB
  // persistent
  float2* rtab = (float2*)(wA + 6 * MB);         // 512 KB at [6:6.5], kept
  // layer-phase aliases (all independent now)
  bf16_t* wqkv = (bf16_t*)wA;                            // [0:6]
  bf16_t* wo   = (bf16_t*)(wA + 6 * MB + 512 * 1024);    // [6.5:8.5]
  bf16_t* w1b  = (bf16_t*)(wA + 9 * MB);                 // [9:17]
  bf16_t* w2b  = (bf16_t*)(wA + 17 * MB);                // [17:25]
  bf16_t* kbuf = (bf16_t*)R;                             // [0:16] during attention
  bf16_t* vt   = (bf16_t*)(R + 16 * MB);                 // [16:32] during attention
  bf16_t* hid  = (bf16_t*)R;                             // 64 MB during MLP

  if (required > ws_size) {
    ylen_kernel<<<dim3(1), 64, 0, stream>>>(x_len, outp + 8L * 1024 * 1024);
    return;
  }

  auto cvt = [&](const float* in, bf16_t* o, long n) {
    cvt_kernel<<<dim3((unsigned)(n / 1024)), 256, 0, stream>>>(in, o, n);
  };

  rtab_kernel<<<dim3(256), 256, 0, stream>>>(rtab);

  // ---- conv stem ----
  cvt(conv1_w, c1w, 1024L * 384);
  cvt(conv2_w, c2w, 1024L * 3072);
  im2col1_kernel<<<dim3((unsigned)((16384L * 384) / 256)), 256, 0, stream>>>(x, a1);
  gemm_bt<EPI_GELU_BF16><<<dim3(128, 8), 512, 0, stream>>>(
      a1, 384, c1w, 384, h1, 1024, conv1_b, nullptr, 384, 1,
      nullptr, nullptr, nullptr, nullptr);
  im2col2_kernel<<<dim3((unsigned)((8192L * 3072) / 256)), 256, 0, stream>>>(h1, a2);
  gemm_bt<EPI_GELU_F32><<<dim3(64, 8), 512, 0, stream>>>(
      a2, 3072, c2w, 3072, outp /*carry*/, 1024, conv2_b, nullptr, 3072, 1,
      nullptr, nullptr, nullptr, nullptr);

  float* carry = outp;  // f32 residual stream lives in d_out

  for (int l = 0; l < 6; ++l) {
    cvt_layer_kernel<<<dim3(12288), 256, 0, stream>>>(
        q_w + (long)l * 1048576, k_w + (long)l * 1048576, v_w + (long)l * 1048576,
        out_w + (long)l * 1048576, mlp1_w + (long)l * 4194304, mlp2_w + (long)l * 4194304,
        wqkv, wo, w1b, w2b);

    ln_kernel<<<dim3(8192), 256, 0, stream>>>(carry, ybuf, attn_ln_w + l * 1024, attn_ln_b + l * 1024);

    // fused QKV projection + rope/scale + V-transpose (N=3072)
    gemm_bt<EPI_QKV><<<dim3(64, 24), 512, 0, stream>>>(
        ybuf, 1024, wqkv, 1024, qbuf, 1024,
        q_b + l * 1024, nullptr, 1024, 1, kbuf, vt, v_b + l * 1024, rtab);

    // flash attention: O overwrites Q in place
    flash_kernel<<<dim3(16, 64), 256, 0, stream>>>(qbuf, kbuf, vt, qbuf, x_len);

    // carry += O @ ow^T + ob
    gemm_bt<EPI_RES_F32><<<dim3(64, 8), 512, 0, stream>>>(
        qbuf, 1024, wo, 1024, carry, 1024,
        out_b + l * 1024, carry, 1024, 1, nullptr, nullptr, nullptr, nullptr);

    ln_kernel<<<dim3(8192), 256, 0, stream>>>(carry, ybuf, mlp_ln_w + l * 1024, mlp_ln_b + l * 1024);

    gemm_bt<EPI_GELU_BF16><<<dim3(64, 32), 512, 0, stream>>>(
        ybuf, 1024, w1b, 1024, hid, 4096,
        mlp1_b + (long)l * 4096, nullptr, 1024, 1, nullptr, nullptr, nullptr, nullptr);
    gemm_bt<EPI_RES_F32><<<dim3(64, 8), 512, 0, stream>>>(
        hid, 4096, w2b, 4096, carry, 1024,
        mlp2_b + l * 1024, carry, 4096, 1, nullptr, nullptr, nullptr, nullptr);
  }

  ylen_kernel<<<dim3(1), 64, 0, stream>>>(x_len, outp + 8L * 1024 * 1024);
}

// Round 12
// 2740.121 us; speedup vs baseline: 1.5091x; 1.0798x over previous
//
#include <hip/hip_runtime.h>
#include <hip/hip_bf16.h>
#include <cstdint>
#include <cstddef>

// ---------------------------------------------------------------------------
// AudioEncoder (Whisper-style) forward for MI355X.
// B=8, T=4096, n_mels=128, D=1024, H=8 heads (hd=128), F=4096, L=6, S=1024.
// GEMMs: 128x128 tile, 8 waves (2Mx4N, 512 threads), BK=32, triple-buffered
// LDS with counted vmcnt(2) + raw barrier; read-side XOR swizzle; 2-D
// square per-XCD chunk remap (16 x gx*gy/128 blocks per XCD -> L2-sized
// working set; r11's 1-D chunks touched ALL A-panels per XCD, 11x over-fetch).
// Attention: flash, KVBLK=32 disjoint double buffers, QBLK=64, 16 waves/CU,
// XCD-locality remap, defer-max, setprio.
// ---------------------------------------------------------------------------

typedef __bf16 bf16_t;
typedef __bf16 bf16x8 __attribute__((ext_vector_type(8)));
typedef __bf16 bf16x4 __attribute__((ext_vector_type(4)));
typedef float  floatx4 __attribute__((ext_vector_type(4)));

#define NB   8
#define NS   1024
#define ND   1024
#define NT   4096
#define NT1  2048

#define MFMA16(a, b, c) __builtin_amdgcn_mfma_f32_16x16x32_bf16(a, b, c, 0, 0, 0)

#define SBAR() do { __builtin_amdgcn_sched_barrier(0); \
                    __builtin_amdgcn_s_barrier();      \
                    __builtin_amdgcn_sched_barrier(0); } while (0)

__device__ __forceinline__ float gelu_f(float x) {
  // tanh-form gelu via sigmoid: 0.5x(1+tanh(z)) = x*sigmoid(2z); |err|<~3e-3
  const float t = 1.5957691216057308f * (x + 0.044715f * x * x * x);
  return x / (1.0f + __expf(-t));
}

__device__ __forceinline__ void gload16(const void* g, void* l) {
  __builtin_amdgcn_global_load_lds(
      (__attribute__((address_space(1))) void*)(const_cast<void*>(g)),
      (__attribute__((address_space(3))) void*)l, 16, 0, 0);
}

enum { EPI_BF16 = 0, EPI_GELU_BF16 = 2, EPI_GELU_F32 = 3, EPI_RES_F32 = 4, EPI_QKV = 5 };

// C = A (M,K) @ B^T, B stored (N,K) row-major. 128x128 tile, 8 waves (2Mx4N),
// each wave 64x32 output as acc[4][2]. 3-buffer LDS pipeline, counted
// vmcnt(2) + raw s_barrier, read-side XOR swizzle.
// swz=1: 2-D per-XCD chunking. id = bx + by*gx round-robins across XCDs, so
// XCD c = id&7 owns ranks r = id>>3. Chunk shape 16(bx) x cby(by), cby =
// gx*gy/128; chunk grid ncx = gx/16 across bx. Requires gx%16==0, gy%cby==0
// (holds for all grids used: 128x8, 64x8, 64x24, 64x32). Bijective.
template<int EPI>
__global__ __launch_bounds__(512)
void gemm_bt(const bf16_t* __restrict__ A, long lda,
             const bf16_t* __restrict__ Bm, long ldb,
             void* Cv, long ldc,
             const float* __restrict__ bias, const float* res,
             int K, int swz,
             bf16_t* out2, bf16_t* out3, const float* __restrict__ bias2,
             const float2* __restrict__ rtab)
{
  __shared__ bf16_t sA[3][4096];   // 3 x 8KB per matrix (48KB total)
  __shared__ bf16_t sB[3][4096];
  const int tid  = threadIdx.x;
  const int wid  = tid >> 6;       // 0..7
  const int lane = tid & 63;
  const int lo = lane & 15, g = lane >> 4;
  const int wr = wid >> 2, wc = wid & 3;   // 2M x 4N wave grid

  int bx = blockIdx.x, by = blockIdx.y;
  if (swz) {
    const int gx = gridDim.x, gy = gridDim.y;
    const int id  = bx + by * gx;
    const int xcd = id & 7;          // dispatch round-robin -> XCD
    const int r   = id >> 3;         // rank within XCD's chunk
    const int cby = (gx * gy) >> 7;  // chunk by-extent (chunk = 16*cby)
    const int ncx = gx >> 4;         // chunks across bx
    const int cx  = xcd % ncx, cy = xcd / ncx;
    bx = cx * 16 + (r & 15);
    by = cy * cby + (r >> 4);
  }
  const int m0 = bx * 128, n0 = by * 128;
  const int NTK = K >> 5;

  const int lrow = lane >> 2;                         // LDS row within segment
  const int lcol = 8 * ((lane & 3) ^ ((lane >> 3) & 3));  // inv-swizzled source

  auto stage = [&](int t) {
    if (t >= NTK) return;
    const int kb = t << 5;
    bf16_t* dA = &sA[t % 3][0];
    bf16_t* dB = &sB[t % 3][0];
    const int seg = wid;             // 8 segments x 16 rows x 64B each matrix
    gload16(A  + (long)(m0 + seg * 16 + lrow) * lda + kb + lcol, dA + seg * 512);
    gload16(Bm + (long)(n0 + seg * 16 + lrow) * ldb + kb + lcol, dB + seg * 512);
  };

  const int rslot = 16 * (g ^ ((lo >> 1) & 3));   // read-side slot XOR (bytes)

  floatx4 acc[4][2] = {};

  stage(0); stage(1);
  asm volatile("s_waitcnt vmcnt(2)" ::: "memory");   // tile0 landed
  SBAR();

#pragma unroll 1
  for (int s = 0; s < NTK; ++s) {
    stage(s + 2);                                    // issue-early prefetch
    const bf16_t* bufA = &sA[s % 3][0];
    const bf16_t* bufB = &sB[s % 3][0];
    bf16x8 av[4], bv[2];
#pragma unroll
    for (int i = 0; i < 4; ++i)
      av[i] = *(const bf16x8*)((const char*)(bufA + (wr * 64 + i * 16 + lo) * 32) + rslot);
#pragma unroll
    for (int i = 0; i < 2; ++i)
      bv[i] = *(const bf16x8*)((const char*)(bufB + (wc * 32 + i * 16 + lo) * 32) + rslot);
#pragma unroll
    for (int mi = 0; mi < 4; ++mi)
#pragma unroll
      for (int ni = 0; ni < 2; ++ni)
        acc[mi][ni] = MFMA16(av[mi], bv[ni], acc[mi][ni]);
    if (s + 2 < NTK) { asm volatile("s_waitcnt vmcnt(2)" ::: "memory"); }
    else             { asm volatile("s_waitcnt vmcnt(0)" ::: "memory"); }
    SBAR();
  }

  // ---- epilogue (wave covers rows wr*64+[0,64), cols wc*32+[0,32)) ----
  if constexpr (EPI == EPI_QKV) {
    const int sect = n0 >> 10;        // 0=Q 1=K 2=V
#pragma unroll
    for (int ni = 0; ni < 2; ++ni) {
      const int col = n0 + wc * 32 + ni * 16 + lo;
      const int c10 = col & 1023;
      float bvs = 0.0f;
      if (sect == 0) bvs = bias[c10];
      else if (sect == 2) bvs = bias2[c10];
#pragma unroll
      for (int mi = 0; mi < 4; ++mi) {
#pragma unroll
        for (int r = 0; r < 4; ++r) {
          const int row = m0 + wr * 64 + mi * 16 + g * 4 + r;
          const int s = row & 1023;
          float val = acc[mi][ni][r] + bvs;
          if (sect < 2) {             // rope + scale (table pre-scaled)
            const float2 t = rtab[(s << 6) + ((col & 127) >> 1)];
            const float p = __shfl_xor(val, 1);
            val = val * t.x + p * ((col & 1) ? t.y : -t.y);
            bf16_t* dst = sect ? out2 : (bf16_t*)Cv;
            dst[(long)row * 1024 + c10] = (bf16_t)val;
          } else {                    // vt[b][h*128+d][s]
            out3[((long)(row >> 10) << 20) + ((long)(col - 2048) << 10) + s] = (bf16_t)val;
          }
        }
      }
    }
    return;
  }

#pragma unroll
  for (int ni = 0; ni < 2; ++ni) {
    const int col = n0 + wc * 32 + ni * 16 + lo;
    const float bvs = bias ? bias[col] : 0.0f;
#pragma unroll
    for (int mi = 0; mi < 4; ++mi) {
#pragma unroll
      for (int r = 0; r < 4; ++r) {
        const int row = m0 + wr * 64 + mi * 16 + g * 4 + r;
        float v = acc[mi][ni][r] + bvs;
        if constexpr (EPI == EPI_BF16) {
          ((bf16_t*)Cv)[(long)row * ldc + col] = (bf16_t)v;
        } else if constexpr (EPI == EPI_GELU_BF16) {
          ((bf16_t*)Cv)[(long)row * ldc + col] = (bf16_t)gelu_f(v);
        } else if constexpr (EPI == EPI_GELU_F32) {
          ((float*)Cv)[(long)row * ldc + col] = gelu_f(v);
        } else {  // EPI_RES_F32
          const long idx = (long)row * ldc + col;
          ((float*)Cv)[idx] = res[idx] + v;
        }
      }
    }
  }
}

// ---------------------------------------------------------------------------
// Flash attention: grid (16, 64), 4 waves/block, wave owns 16 q-rows.
// KVBLK=32: true disjoint double buffers. LDS 36KB -> 4 blocks/CU with
// __launch_bounds__(256,4). Swizzles: K rows XOR (row&7)<<4 (256B rows);
// V/P rows XOR (row&3)<<4 (64B rows); inverse-swizzled global source.
// XCD remap: hid = bx + by*16; h = hid&7; qx = (hid>>3)&15; b = hid>>7.
// ---------------------------------------------------------------------------
__global__ __launch_bounds__(256, 4)
void flash_kernel(const bf16_t* __restrict__ q, const bf16_t* __restrict__ k,
                  const bf16_t* __restrict__ vt, bf16_t* __restrict__ o,
                  const int* __restrict__ xlen)
{
  __shared__ bf16_t sK[2][4096];   // [buf][kv=32][d=128]
  __shared__ bf16_t sV[2][4096];   // [buf][d=128][kv=32]
  __shared__ bf16_t sP[4][512];    // per-wave [q=16][kv=32]
  const int tid = threadIdx.x, w = tid >> 6, lane = tid & 63;
  const int lo = lane & 15, g = lane >> 4;
  const int hid = blockIdx.x + (blockIdx.y << 4);
  const int h   = hid & 7;
  const int qx  = (hid >> 3) & 15;
  const int b   = hid >> 7;
  const int q0 = qx * 64 + w * 16;
  const int nv  = xlen[b] >> 2;            // valid kv columns (>= 512)
  const int nkt = (nv + 31) >> 5;          // tiles of 32
  const long base = (long)b * 1048576 + (long)h * 128;
  const bf16_t* Qp = q + base;
  const bf16_t* Kp = k + base;
  const bf16_t* Vp = vt + (long)b * 1048576 + ((long)h << 17);  // [d][s]

  auto stageKV = [&](int kt, int buf) {
    const int kv0 = kt << 5;
#pragma unroll
    for (int jj = 0; jj < 2; ++jj) {
      const int seg = (w << 1) + jj;                 // 0..7, wave-uniform
      {
        const int row = (seg << 2) + (lane >> 4);    // kv row 0..31
        const int col = ((lane & 15) << 3) ^ ((row & 7) << 3);   // elems
        gload16(Kp + (long)(kv0 + row) * 1024 + col, &sK[buf][seg * 512]);
      }
      {
        const int row = (seg << 4) + (lane >> 2);    // d row 0..127
        const int col = ((lane & 3) << 3) ^ ((row & 3) << 3);    // elems < 32
        gload16(Vp + (long)row * 1024 + kv0 + col, &sV[buf][seg * 512]);
      }
    }
  };

  bf16x8 qf[4];
#pragma unroll
  for (int ks = 0; ks < 4; ++ks)
    qf[ks] = *reinterpret_cast<const bf16x8*>(
        Qp + (long)(q0 + lo) * 1024 + ks * 32 + g * 8);

  floatx4 of[8] = {};
  float m[4], l[4];
#pragma unroll
  for (int r = 0; r < 4; ++r) { m[r] = -1e30f; l[r] = 0.0f; }

  const char* kbase = (const char*)&sK[0][0];
  const char* vbase = (const char*)&sV[0][0];
  char* pbase = (char*)&sP[w][0];
  const int swzK = (lo & 7) << 4;   // K rows: 256B, XOR bits 4-6
  const int swzV = (lo & 3) << 4;   // V/P rows: 64B, XOR bits 4-5

  stageKV(0, 0);
  __syncthreads();
  int cur = 0;
#pragma unroll 1
  for (int kt = 0; kt < nkt; ++kt) {
    const int kv0 = kt << 5;
    if (kt + 1 < nkt) stageKV(kt + 1, cur ^ 1);

    // S = Q @ K^T over 32 kv cols (8 MFMA)
    floatx4 s[2] = {};
    __builtin_amdgcn_s_setprio(1);
#pragma unroll
    for (int ni = 0; ni < 2; ++ni) {
#pragma unroll
      for (int ks = 0; ks < 4; ++ks) {
        const bf16x8 bv = *reinterpret_cast<const bf16x8*>(
            kbase + cur * 8192 + (ni * 16 + lo) * 256 + ((ks * 64 + (g << 4)) ^ swzK));
        s[ni] = MFMA16(qf[ks], bv, s[ni]);
      }
    }
    __builtin_amdgcn_s_setprio(0);

    // per-row masked max, then wave-uniform defer-max vote
    float pmv[4];
#pragma unroll
    for (int r = 0; r < 4; ++r) {
      float pm = -1e30f;
#pragma unroll
      for (int ni = 0; ni < 2; ++ni) {
        float val = s[ni][r];
        if (kv0 + ni * 16 + lo >= nv) val = -1e30f;
        pm = fmaxf(pm, val);
      }
      pm = fmaxf(pm, __shfl_xor(pm, 1)); pm = fmaxf(pm, __shfl_xor(pm, 2));
      pm = fmaxf(pm, __shfl_xor(pm, 4)); pm = fmaxf(pm, __shfl_xor(pm, 8));
      pmv[r] = pm;
    }
    const bool skip = __all((pmv[0] <= m[0] + 8.0f) & (pmv[1] <= m[1] + 8.0f) &
                            (pmv[2] <= m[2] + 8.0f) & (pmv[3] <= m[3] + 8.0f));

#pragma unroll
    for (int r = 0; r < 4; ++r) {
      float mn = m[r];
      if (!skip) {
        mn = fmaxf(m[r], pmv[r]);
        const float sc = __expf(m[r] - mn);
        l[r] *= sc;
#pragma unroll
        for (int nd = 0; nd < 8; ++nd) of[nd][r] *= sc;
        m[r] = mn;
      }
      const int qrow = g * 4 + r;
      const int sw = (qrow & 3) << 4;
      float ss = 0.0f;
#pragma unroll
      for (int ni = 0; ni < 2; ++ni) {
        float val = s[ni][r];
        if (kv0 + ni * 16 + lo >= nv) val = -1e30f;
        const float p = __expf(val - mn);
        ss += p;
        *(bf16_t*)(pbase + qrow * 64 + (((ni << 5) + (lo << 1)) ^ sw)) = (bf16_t)p;
      }
      ss += __shfl_xor(ss, 1); ss += __shfl_xor(ss, 2);
      ss += __shfl_xor(ss, 4); ss += __shfl_xor(ss, 8);
      l[r] += ss;
    }

    // RAW: P writes visible before A-frag reads (rule 18: + sched_barrier)
    asm volatile("s_waitcnt lgkmcnt(0)" ::: "memory");
    __builtin_amdgcn_sched_barrier(0);

    // O += P @ V (8 MFMA, single K=32 step)
    __builtin_amdgcn_s_setprio(1);
    {
      const bf16x8 av = *reinterpret_cast<const bf16x8*>(
          pbase + lo * 64 + ((g << 4) ^ swzV));
#pragma unroll
      for (int nd = 0; nd < 8; ++nd) {
        const bf16x8 bv = *reinterpret_cast<const bf16x8*>(
            vbase + cur * 8192 + (nd * 16 + lo) * 64 + ((g << 4) ^ swzV));
        of[nd] = MFMA16(av, bv, of[nd]);
      }
    }
    __builtin_amdgcn_s_setprio(0);
    __syncthreads();   // drains gload (next tile landed) + all LDS reads done
    cur ^= 1;
  }

  // epilogue: normalize and write O (in place over Q region)
#pragma unroll
  for (int r = 0; r < 4; ++r) {
    const float inv = 1.0f / l[r];
    const long rb = base + (long)(q0 + g * 4 + r) * 1024;
#pragma unroll
    for (int nd = 0; nd < 8; ++nd)
      o[rb + nd * 16 + lo] = (bf16_t)(of[nd][r] * inv);
  }
}

// LayerNorm: one block per row of 1024 f32 -> bf16
__global__ __launch_bounds__(256)
void ln_kernel(const float* __restrict__ x, bf16_t* __restrict__ y,
               const float* __restrict__ w, const float* __restrict__ b)
{
  const long row = blockIdx.x;
  const float4 v = reinterpret_cast<const float4*>(x + row * ND)[threadIdx.x];
  float s  = v.x + v.y + v.z + v.w;
  float ss = v.x * v.x + v.y * v.y + v.z * v.z + v.w * v.w;
#pragma unroll
  for (int off = 32; off; off >>= 1) { s += __shfl_down(s, off); ss += __shfl_down(ss, off); }
  __shared__ float sh[8];
  if ((threadIdx.x & 63) == 0) { sh[threadIdx.x >> 6] = s; sh[4 + (threadIdx.x >> 6)] = ss; }
  __syncthreads();
  const float tot  = sh[0] + sh[1] + sh[2] + sh[3];
  const float tot2 = sh[4] + sh[5] + sh[6] + sh[7];
  const float mean = tot * (1.0f / ND);
  const float var  = tot2 * (1.0f / ND) - mean * mean;
  const float rstd = rsqrtf(var + 1e-5f);
  const int i0 = threadIdx.x * 4;
  const float vv[4] = {v.x, v.y, v.z, v.w};
  bf16x4 o;
#pragma unroll
  for (int j = 0; j < 4; ++j)
    o[j] = (bf16_t)((vv[j] - mean) * rstd * w[i0 + j] + b[i0 + j]);
  reinterpret_cast<bf16x4*>(y + row * ND)[threadIdx.x] = o;
}

// pre-scaled rope table: rtab[s*64+i] = (cos, sin)(s*f_i) * 128^-0.25
__global__ __launch_bounds__(256)
void rtab_kernel(float2* __restrict__ tab)
{
  const int idx = blockIdx.x * 256 + threadIdx.x;   // 65536
  const int s = idx >> 6, i = idx & 63;
  const float freq = __expf((float)i * -0.14391156831212787f);  // 10000^(-2i/128)
  float sn, cs;
  sincosf((float)s * freq, &sn, &cs);
  const float sc = 0.29730177875068026f;
  tab[idx] = make_float2(cs * sc, sn * sc);
}

// im2col conv1: A1[(b*2048+t), i*3+kk] = x[b, i, 2t+kk-1] (pad 1), f32->bf16
__global__ __launch_bounds__(256)
void im2col1_kernel(const float* __restrict__ x, bf16_t* __restrict__ a)
{
  const long idx = (long)blockIdx.x * 256 + threadIdx.x;
  if (idx >= (long)NB * NT1 * 384) return;
  const int  k = (int)(idx % 384);
  const long m = idx / 384;
  const int i = k / 3, kk = k - 3 * i;
  const int t = (int)(m & (NT1 - 1));
  const int b = (int)(m >> 11);
  const int tt = 2 * t + kk - 1;
  float v = 0.0f;
  if (tt >= 0 && tt < NT) v = x[((long)b * 128 + i) * NT + tt];
  a[idx] = (bf16_t)v;
}

// im2col conv2: A2[(b*1024+t), i*3+kk] = h1[b, 2t+kk-1, i] (pad 1)
__global__ __launch_bounds__(256)
void im2col2_kernel(const bf16_t* __restrict__ h1, bf16_t* __restrict__ a)
{
  const long idx = (long)blockIdx.x * 256 + threadIdx.x;
  if (idx >= (long)NB * NS * 3072) return;
  const int  k = (int)(idx % 3072);
  const long m = idx / 3072;
  const int i = k / 3, kk = k - 3 * i;
  const int t = (int)(m & (NS - 1));
  const int b = (int)(m >> 10);
  const int tt = 2 * t + kk - 1;
  bf16_t v = (bf16_t)0.0f;
  if (tt >= 0 && tt < NT1) v = h1[((long)b * NT1 + tt) * ND + i];
  a[idx] = v;
}

__global__ void ylen_kernel(const int* __restrict__ xlen, float* __restrict__ ylen)
{
  const int b = threadIdx.x;
  if (b < NB) {
    const int y1 = (xlen[b] + 1) >> 1;
    ylen[b] = (float)((y1 + 1) >> 1);
  }
}

__global__ __launch_bounds__(256)
void cvt_kernel(const float* __restrict__ in, bf16_t* __restrict__ out, long n)
{
  const long i = ((long)blockIdx.x * 256 + threadIdx.x) * 4;
  if (i >= n) return;
  const float4 v = *reinterpret_cast<const float4*>(in + i);
  bf16x4 o;
  o[0] = (bf16_t)v.x; o[1] = (bf16_t)v.y; o[2] = (bf16_t)v.z; o[3] = (bf16_t)v.w;
  *reinterpret_cast<bf16x4*>(out + i) = o;
}

// per-layer weight conversion in ONE launch: q,k,v -> wqkv (3M elems),
// ow -> wo (1M), w1 -> w1b (4M), w2 -> w2b (4M). 12M elems total.
__global__ __launch_bounds__(256)
void cvt_layer_kernel(const float* __restrict__ qw, const float* __restrict__ kw,
                      const float* __restrict__ vw, const float* __restrict__ ow,
                      const float* __restrict__ w1, const float* __restrict__ w2,
                      bf16_t* __restrict__ wqkv, bf16_t* __restrict__ wo,
                      bf16_t* __restrict__ w1b, bf16_t* __restrict__ w2b)
{
  const long i = ((long)blockIdx.x * 256 + threadIdx.x) * 4;
  const float* src; bf16_t* dst;
  if (i < 3145728) {
    dst = wqkv + i;
    if (i < 1048576)      { src = qw + i; }
    else if (i < 2097152) { src = kw + (i - 1048576); }
    else                  { src = vw + (i - 2097152); }
  } else if (i < 4194304) { src = ow + (i - 3145728); dst = wo  + (i - 3145728); }
  else if (i < 8388608)   { src = w1 + (i - 4194304); dst = w1b + (i - 4194304); }
  else                    { src = w2 + (i - 8388608); dst = w2b + (i - 8388608); }
  const float4 v = *reinterpret_cast<const float4*>(src);
  bf16x4 o;
  o[0] = (bf16_t)v.x; o[1] = (bf16_t)v.y; o[2] = (bf16_t)v.z; o[3] = (bf16_t)v.w;
  *reinterpret_cast<bf16x4*>(dst) = o;
}

extern "C" void kernel_launch(void* const* d_in, const int* in_sizes, int n_in,
                              void* d_out, int out_size, void* d_ws, size_t ws_size,
                              hipStream_t stream)
{
  const float* x         = (const float*)d_in[0];
  const int*   x_len     = (const int*)  d_in[1];
  const float* conv1_w   = (const float*)d_in[2];
  const float* conv1_b   = (const float*)d_in[3];
  const float* conv2_w   = (const float*)d_in[4];
  const float* conv2_b   = (const float*)d_in[5];
  const float* attn_ln_w = (const float*)d_in[6];
  const float* attn_ln_b = (const float*)d_in[7];
  const float* q_w   = (const float*)d_in[8];
  const float* q_b   = (const float*)d_in[9];
  const float* k_w   = (const float*)d_in[10];
  const float* v_w   = (const float*)d_in[11];
  const float* v_b   = (const float*)d_in[12];
  const float* out_w = (const float*)d_in[13];
  const float* out_b = (const float*)d_in[14];
  const float* mlp_ln_w = (const float*)d_in[15];
  const float* mlp_ln_b = (const float*)d_in[16];
  const float* mlp1_w = (const float*)d_in[17];
  const float* mlp1_b = (const float*)d_in[18];
  const float* mlp2_w = (const float*)d_in[19];
  const float* mlp2_b = (const float*)d_in[20];
  float* outp = (float*)d_out;
  (void)in_sizes; (void)n_in; (void)out_size;

  const long MB = 1024L * 1024;
  char* ws = (char*)d_ws;
  size_t off = 0;
  auto alloc = [&](size_t bytes) -> char* {
    char* p = ws + off;
    off += (bytes + 255) & ~(size_t)255;
    return p;
  };
  bf16_t* ybuf  = (bf16_t*)alloc(16 * MB);       //  16 MB | a1(conv)
  bf16_t* qbuf  = (bf16_t*)alloc(16 * MB);       //  16 MB | h1[0:16] | Q then O
  char*   R     = alloc(64 * MB);                //  64 MB | h1[16:32]+a2 | kbuf+vt | hid
  char*   wA    = alloc(25 * MB);                //  25 MB | weights/rtab
  const size_t required = off;                   // ~121 MB

  // conv-phase aliases
  bf16_t* a1  = ybuf;                            // 12 MB
  bf16_t* h1  = qbuf;                            // 32 MB (qbuf + R[0:16])
  bf16_t* a2  = (bf16_t*)(R + 16 * MB);          // 48 MB
  bf16_t* c2w = (bf16_t*)wA;                     //  6 MB
  bf16_t* c1w = (bf16_t*)(wA + 8 * MB);          // 0.75 MB
  // persistent
  float2* rtab = (float2*)(wA + 6 * MB);         // 512 KB at [6:6.5], kept
  // layer-phase aliases (all independent now)
  bf16_t* wqkv = (bf16_t*)wA;                            // [0:6]
  bf16_t* wo   = (bf16_t*)(wA + 6 * MB + 512 * 1024);    // [6.5:8.5]
  bf16_t* w1b  = (bf16_t*)(wA + 9 * MB);                 // [9:17]
  bf16_t* w2b  = (bf16_t*)(wA + 17 * MB);                // [17:25]
  bf16_t* kbuf = (bf16_t*)R;                             // [0:16] during attention
  bf16_t* vt   = (bf16_t*)(R + 16 * MB);                 // [16:32] during attention
  bf16_t* hid  = (bf16_t*)R;                             // 64 MB during MLP

  if (required > ws_size) {
    ylen_kernel<<<dim3(1), 64, 0, stream>>>(x_len, outp + 8L * 1024 * 1024);
    return;
  }

  auto cvt = [&](const float* in, bf16_t* o, long n) {
    cvt_kernel<<<dim3((unsigned)(n / 1024)), 256, 0, stream>>>(in, o, n);
  };

  rtab_kernel<<<dim3(256), 256, 0, stream>>>(rtab);

  // ---- conv stem ----
  cvt(conv1_w, c1w, 1024L * 384);
  cvt(conv2_w, c2w, 1024L * 3072);
  im2col1_kernel<<<dim3((unsigned)((16384L * 384) / 256)), 256, 0, stream>>>(x, a1);
  gemm_bt<EPI_GELU_BF16><<<dim3(128, 8), 512, 0, stream>>>(
      a1, 384, c1w, 384, h1, 1024, conv1_b, nullptr, 384, 1,
      nullptr, nullptr, nullptr, nullptr);
  im2col2_kernel<<<dim3((unsigned)((8192L * 3072) / 256)), 256, 0, stream>>>(h1, a2);
  gemm_bt<EPI_GELU_F32><<<dim3(64, 8), 512, 0, stream>>>(
      a2, 3072, c2w, 3072, outp /*carry*/, 1024, conv2_b, nullptr, 3072, 1,
      nullptr, nullptr, nullptr, nullptr);

  float* carry = outp;  // f32 residual stream lives in d_out

  for (int l = 0; l < 6; ++l) {
    cvt_layer_kernel<<<dim3(12288), 256, 0, stream>>>(
        q_w + (long)l * 1048576, k_w + (long)l * 1048576, v_w + (long)l * 1048576,
        out_w + (long)l * 1048576, mlp1_w + (long)l * 4194304, mlp2_w + (long)l * 4194304,
        wqkv, wo, w1b, w2b);

    ln_kernel<<<dim3(8192), 256, 0, stream>>>(carry, ybuf, attn_ln_w + l * 1024, attn_ln_b + l * 1024);

    // fused QKV projection + rope/scale + V-transpose (N=3072)
    gemm_bt<EPI_QKV><<<dim3(64, 24), 512, 0, stream>>>(
        ybuf, 1024, wqkv, 1024, qbuf, 1024,
        q_b + l * 1024, nullptr, 1024, 1, kbuf, vt, v_b + l * 1024, rtab);

    // flash attention: O overwrites Q in place
    flash_kernel<<<dim3(16, 64), 256, 0, stream>>>(qbuf, kbuf, vt, qbuf, x_len);

    // carry += O @ ow^T + ob
    gemm_bt<EPI_RES_F32><<<dim3(64, 8), 512, 0, stream>>>(
        qbuf, 1024, wo, 1024, carry, 1024,
        out_b + l * 1024, carry, 1024, 1, nullptr, nullptr, nullptr, nullptr);

    ln_kernel<<<dim3(8192), 256, 0, stream>>>(carry, ybuf, mlp_ln_w + l * 1024, mlp_ln_b + l * 1024);

    gemm_bt<EPI_GELU_BF16><<<dim3(64, 32), 512, 0, stream>>>(
        ybuf, 1024, w1b, 1024, hid, 4096,
        mlp1_b + (long)l * 4096, nullptr, 1024, 1, nullptr, nullptr, nullptr, nullptr);
    gemm_bt<EPI_RES_F32><<<dim3(64, 8), 512, 0, stream>>>(
        hid, 4096, w2b, 4096, carry, 1024,
        mlp2_b + l * 1024, carry, 4096, 1, nullptr, nullptr, nullptr, nullptr);
  }

  ylen_kernel<<<dim3(1), 64, 0, stream>>>(x_len, outp + 8L * 1024 * 1024);
}